// Round 1
// baseline (1349.892 us; speedup 1.0000x reference)
//
#include <hip/hip_runtime.h>
#include <math.h>

#define NS 20000
#define TT 6890
#define FE 128
#define EDG 640000
#define DEG 32
#define BR 64
#define BT 64
#define SROW 132   // 128 + 4 pad: 16B-aligned rows, bank-stride 4 -> <=2-way conflicts (free)

// ---------------- K0: target squared norms ----------------
__global__ void tn_kernel(const float* __restrict__ tf, float* __restrict__ tn) {
  int gid = blockIdx.x * blockDim.x + threadIdx.x;
  int w = gid >> 6;
  int lane = gid & 63;
  if (w >= TT) return;
  const float* p = tf + w * FE;
  float a = p[lane];
  float b = p[lane + 64];
  float s = a * a + b * b;
#pragma unroll
  for (int off = 32; off > 0; off >>= 1) s += __shfl_xor(s, off);
  if (lane == 0) tn[w] = s;
}

// ---------------- K1: fused GEMM + top-6 + softmax gather ----------------
union __align__(16) Smem {
  struct {
    float s[BR][SROW];
    float t[BT][SROW];
    float tnl[BT];
  } a;
  struct {          // merge buffers (reuse tile space after compute)
    float cd[BR][97];
    int   ci[BR][97];
  } b;
};

__global__ __launch_bounds__(256) void topk_kernel(
    const float* __restrict__ sf, const float* __restrict__ tf,
    const float* __restrict__ tn, const float* __restrict__ tp,
    float* __restrict__ pred) {
  __shared__ Smem sm;
  const int tid = threadIdx.x;
  const int row0 = blockIdx.x * BR;
  const int tr = tid >> 4;   // 0..15
  const int tc = tid & 15;   // 0..15

  // load S tile (full K=128 resident)
#pragma unroll
  for (int k = 0; k < 8; ++k) {
    int idx = tid + k * 256;
    int r = idx >> 5;
    int f4 = (idx & 31) << 2;
    int gr = row0 + r;
    float4 v = make_float4(0.f, 0.f, 0.f, 0.f);
    if (gr < NS) v = *reinterpret_cast<const float4*>(sf + gr * FE + f4);
    *reinterpret_cast<float4*>(&sm.a.s[r][f4]) = v;
  }

  float bd[4][6];
  int   bi[4][6];
#pragma unroll
  for (int i = 0; i < 4; ++i)
#pragma unroll
    for (int k = 0; k < 6; ++k) { bd[i][k] = 1e30f; bi[i][k] = 0; }

  for (int t0 = 0; t0 < TT; t0 += BT) {
    __syncthreads();
#pragma unroll
    for (int k = 0; k < 8; ++k) {
      int idx = tid + k * 256;
      int c = idx >> 5;
      int f4 = (idx & 31) << 2;
      int gc = t0 + c;
      float4 v = make_float4(0.f, 0.f, 0.f, 0.f);
      if (gc < TT) v = *reinterpret_cast<const float4*>(tf + gc * FE + f4);
      *reinterpret_cast<float4*>(&sm.a.t[c][f4]) = v;
    }
    if (tid < BT) {
      int gc = t0 + tid;
      sm.a.tnl[tid] = (gc < TT) ? tn[gc] : 1e30f;
    }
    __syncthreads();

    float acc[4][4];
#pragma unroll
    for (int i = 0; i < 4; ++i)
#pragma unroll
      for (int j = 0; j < 4; ++j) acc[i][j] = 0.f;

#pragma unroll 4
    for (int f4 = 0; f4 < FE; f4 += 4) {
      float4 sv[4], tv[4];
#pragma unroll
      for (int i = 0; i < 4; ++i)
        sv[i] = *reinterpret_cast<const float4*>(&sm.a.s[tr + 16 * i][f4]);
#pragma unroll
      for (int j = 0; j < 4; ++j)
        tv[j] = *reinterpret_cast<const float4*>(&sm.a.t[tc + 16 * j][f4]);
#pragma unroll
      for (int i = 0; i < 4; ++i)
#pragma unroll
        for (int j = 0; j < 4; ++j)
          acc[i][j] += sv[i].x * tv[j].x + sv[i].y * tv[j].y +
                       sv[i].z * tv[j].z + sv[i].w * tv[j].w;
    }

    // top-k update (per-row constant ||s||^2 dropped: shift-invariant)
#pragma unroll
    for (int j = 0; j < 4; ++j) {
      int c = tc + 16 * j;
      float tnv = sm.a.tnl[c];
      int gidx = t0 + c;
#pragma unroll
      for (int i = 0; i < 4; ++i) {
        float d = tnv - 2.f * acc[i][j];
        if (d < bd[i][5]) {
          bd[i][5] = d; bi[i][5] = gidx;
#pragma unroll
          for (int k = 4; k >= 0; --k) {
            if (bd[i][k + 1] < bd[i][k]) {
              float td_ = bd[i][k]; bd[i][k] = bd[i][k + 1]; bd[i][k + 1] = td_;
              int ti_ = bi[i][k]; bi[i][k] = bi[i][k + 1]; bi[i][k + 1] = ti_;
            }
          }
        }
      }
    }
  }

  __syncthreads();
  // dump per-thread candidates: 16 threads x 6 entries per row
#pragma unroll
  for (int i = 0; i < 4; ++i) {
    int r = tr + 16 * i;
#pragma unroll
    for (int k = 0; k < 6; ++k) {
      sm.b.cd[r][tc * 6 + k] = bd[i][k];
      sm.b.ci[r][tc * 6 + k] = bi[i][k];
    }
  }
  __syncthreads();
  if (tid < BR) {
    int grow = row0 + tid;
    if (grow < NS) {
      float sd[6]; int si[6];
#pragma unroll
      for (int k = 0; k < 6; ++k) {
        float best = 1e30f; int bpos = 0;
        for (int m = 0; m < 96; ++m) {
          float d = sm.b.cd[tid][m];
          if (d < best) { best = d; bpos = m; }
        }
        sd[k] = best; si[k] = sm.b.ci[tid][bpos];
        sm.b.cd[tid][bpos] = 1e30f;
      }
      float w[6]; float wsum = 0.f;
#pragma unroll
      for (int k = 0; k < 6; ++k) { w[k] = __expf(sd[0] - sd[k]); wsum += w[k]; }
      float inv = 1.f / wsum;
      float px = 0.f, py = 0.f, pz = 0.f;
#pragma unroll
      for (int k = 0; k < 6; ++k) {
        float s = w[k] * inv;
        const float* q = tp + si[k] * 3;
        px += s * q[0]; py += s * q[1]; pz += s * q[2];
      }
      pred[grow * 3 + 0] = px;
      pred[grow * 3 + 1] = py;
      pred[grow * 3 + 2] = pz;
    }
  }
}

// ---------------- K2: per-node Procrustes (3x3 SVD, fp64 Jacobi) ----------------
__global__ __launch_bounds__(256) void proc_kernel(
    const int* __restrict__ colp, const float* __restrict__ pos,
    const float* __restrict__ pred, float* __restrict__ Rout,
    float* __restrict__ tout, float* __restrict__ qnorm) {
  int i = blockIdx.x * blockDim.x + threadIdx.x;
  if (i >= NS) return;
  double sp[3] = {0, 0, 0}, sq[3] = {0, 0, 0};
  double spq[3][3] = {{0, 0, 0}, {0, 0, 0}, {0, 0, 0}};
  const int* ci = colp + i * DEG;
  for (int e = 0; e < DEG; ++e) {
    int c = ci[e];
    double p0 = pos[c * 3], p1 = pos[c * 3 + 1], p2 = pos[c * 3 + 2];
    double q0 = pred[c * 3], q1 = pred[c * 3 + 1], q2 = pred[c * 3 + 2];
    sp[0] += p0; sp[1] += p1; sp[2] += p2;
    sq[0] += q0; sq[1] += q1; sq[2] += q2;
    spq[0][0] += p0 * q0; spq[0][1] += p0 * q1; spq[0][2] += p0 * q2;
    spq[1][0] += p1 * q0; spq[1][1] += p1 * q1; spq[1][2] += p1 * q2;
    spq[2][0] += p2 * q0; spq[2][1] += p2 * q1; spq[2][2] += p2 * q2;
  }
  const double inv = 1.0 / 32.0;
  double A[3][3], sc[3], tcn[3];
  for (int a = 0; a < 3; ++a) {
    sc[a] = sp[a] * inv;
    tcn[a] = sq[a] * inv;
  }
  for (int a = 0; a < 3; ++a)
    for (int b = 0; b < 3; ++b) A[a][b] = spq[a][b] - sp[a] * sq[b] * inv;

  // S = A^T A, Jacobi eigendecomposition -> V (columns), eigenvalues
  double S[3][3];
  for (int a = 0; a < 3; ++a)
    for (int b = 0; b < 3; ++b)
      S[a][b] = A[0][a] * A[0][b] + A[1][a] * A[1][b] + A[2][a] * A[2][b];
  double V[3][3] = {{1, 0, 0}, {0, 1, 0}, {0, 0, 1}};
  const int JP[3] = {0, 0, 1}, JQ[3] = {1, 2, 2};
  for (int sweep = 0; sweep < 10; ++sweep) {
    for (int r = 0; r < 3; ++r) {
      int p = JP[r], q = JQ[r];
      double apq = S[p][q];
      if (fabs(apq) < 1e-300) continue;
      double theta = (S[q][q] - S[p][p]) / (2.0 * apq);
      double t = copysign(1.0 / (fabs(theta) + sqrt(theta * theta + 1.0)), theta);
      double c = 1.0 / sqrt(t * t + 1.0);
      double s = t * c;
      double spp = S[p][p], sqq = S[q][q];
      S[p][p] = spp - t * apq;
      S[q][q] = sqq + t * apq;
      S[p][q] = 0.0; S[q][p] = 0.0;
      int k = 3 - p - q;
      double skp = S[k][p], skq = S[k][q];
      S[k][p] = S[p][k] = c * skp - s * skq;
      S[k][q] = S[q][k] = s * skp + c * skq;
      for (int m = 0; m < 3; ++m) {
        double vp = V[m][p], vq = V[m][q];
        V[m][p] = c * vp - s * vq;
        V[m][q] = s * vp + c * vq;
      }
    }
  }
  double lam[3] = {S[0][0], S[1][1], S[2][2]};
  int i0 = 0, i1 = 1, i2 = 2, tmp;
  if (lam[i0] < lam[i1]) { tmp = i0; i0 = i1; i1 = tmp; }
  if (lam[i0] < lam[i2]) { tmp = i0; i0 = i2; i2 = tmp; }
  if (lam[i1] < lam[i2]) { tmp = i1; i1 = i2; i2 = tmp; }
  double v0[3] = {V[0][i0], V[1][i0], V[2][i0]};
  double v1[3] = {V[0][i1], V[1][i1], V[2][i1]};
  double v2[3] = {V[0][i2], V[1][i2], V[2][i2]};

  double Av0[3], Av1[3], Av2[3];
  for (int a = 0; a < 3; ++a) {
    Av0[a] = A[a][0] * v0[0] + A[a][1] * v0[1] + A[a][2] * v0[2];
    Av1[a] = A[a][0] * v1[0] + A[a][1] * v1[1] + A[a][2] * v1[2];
    Av2[a] = A[a][0] * v2[0] + A[a][1] * v2[1] + A[a][2] * v2[2];
  }
  double n0 = fmax(sqrt(Av0[0]*Av0[0] + Av0[1]*Av0[1] + Av0[2]*Av0[2]), 1e-300);
  double u0[3] = {Av0[0] / n0, Av0[1] / n0, Av0[2] / n0};
  double proj = u0[0]*Av1[0] + u0[1]*Av1[1] + u0[2]*Av1[2];
  double u1[3] = {Av1[0] - proj * u0[0], Av1[1] - proj * u0[1], Av1[2] - proj * u0[2]};
  double n1 = fmax(sqrt(u1[0]*u1[0] + u1[1]*u1[1] + u1[2]*u1[2]), 1e-300);
  u1[0] /= n1; u1[1] /= n1; u1[2] /= n1;
  double w[3] = {u0[1]*u1[2] - u0[2]*u1[1],
                 u0[2]*u1[0] - u0[0]*u1[2],
                 u0[0]*u1[1] - u0[1]*u1[0]};
  double dotw = Av2[0]*w[0] + Av2[1]*w[1] + Av2[2]*w[2];
  double sgn = (dotw < 0.0) ? -1.0 : 1.0;
  double detA = A[0][0]*(A[1][1]*A[2][2] - A[1][2]*A[2][1])
              - A[0][1]*(A[1][0]*A[2][2] - A[1][2]*A[2][0])
              + A[0][2]*(A[1][0]*A[2][1] - A[1][1]*A[2][0]);
  double d3 = ((detA < 0.0) ? -1.0 : 1.0) * sgn;

  double R[3][3];
  for (int a = 0; a < 3; ++a)
    for (int b = 0; b < 3; ++b)
      R[a][b] = u0[a]*v0[b] + u1[a]*v1[b] + d3 * w[a]*v2[b];

  for (int a = 0; a < 3; ++a)
    for (int b = 0; b < 3; ++b) Rout[i * 9 + a * 3 + b] = (float)R[a][b];
  double tr_[3];
  for (int a = 0; a < 3; ++a) {
    tr_[a] = tcn[a] - (R[a][0]*sc[0] + R[a][1]*sc[1] + R[a][2]*sc[2]);
    tout[i * 3 + a] = (float)tr_[a];
  }
  // residual at this node under its own transform (reused by all edges pointing here)
  double pxi = pos[i * 3], pyi = pos[i * 3 + 1], pzi = pos[i * 3 + 2];
  double r0 = R[0][0]*pxi + R[0][1]*pyi + R[0][2]*pzi + tr_[0] - pred[i * 3];
  double r1 = R[1][0]*pxi + R[1][1]*pyi + R[1][2]*pzi + tr_[1] - pred[i * 3 + 1];
  double r2 = R[2][0]*pxi + R[2][1]*pyi + R[2][2]*pzi + tr_[2] - pred[i * 3 + 2];
  qnorm[i] = (float)(r0 * r0 + r1 * r1 + r2 * r2);
}

// ---------------- K3: per-node residual mean over neighbors ----------------
__global__ __launch_bounds__(256) void dst_kernel(
    const int* __restrict__ colp, const float* __restrict__ qn,
    float* __restrict__ dout) {
  int i = blockIdx.x * blockDim.x + threadIdx.x;
  if (i >= NS) return;
  const int* ci = colp + i * DEG;
  float s = 0.f;
#pragma unroll
  for (int e = 0; e < DEG; ++e) s += qn[ci[e]];
  dout[i] = s * (1.0f / 32.0f);
}

extern "C" void kernel_launch(void* const* d_in, const int* in_sizes, int n_in,
                              void* d_out, int out_size, void* d_ws, size_t ws_size,
                              hipStream_t stream) {
  const float* sf  = (const float*)d_in[0];   // [N,128]
  const float* tf  = (const float*)d_in[1];   // [T,128]
  const float* tp  = (const float*)d_in[2];   // [T,3]
  const float* pos = (const float*)d_in[3];   // [N,3]
  const int*   ei  = (const int*)d_in[4];     // [2,E]
  float* out = (float*)d_out;                 // [N*9 | N*3 | N]
  char* ws = (char*)d_ws;
  float* tn   = (float*)(ws);                 // T floats
  float* pred = (float*)(ws + 32768);         // N*3 floats
  float* qn   = (float*)(ws + 32768 + 240000);// N floats
  const int* colp = ei + EDG;

  tn_kernel<<<(TT * 64 + 255) / 256, 256, 0, stream>>>(tf, tn);
  topk_kernel<<<(NS + BR - 1) / BR, 256, 0, stream>>>(sf, tf, tn, tp, pred);
  proc_kernel<<<(NS + 255) / 256, 256, 0, stream>>>(colp, pos, pred, out,
                                                    out + NS * 9, qn);
  dst_kernel<<<(NS + 255) / 256, 256, 0, stream>>>(colp, qn, out + NS * 12);
}

// Round 2
// 784.557 us; speedup vs baseline: 1.7206x; 1.7206x over previous
//
#include <hip/hip_runtime.h>
#include <math.h>

#define NS 20000
#define TT 6890
#define FE 128
#define EDG 640000
#define DEG 32

#define BRR 64      // rows per block
#define BTT 64      // target cols per strip
#define AST 136     // LDS row stride for bf16 tiles (128 + 8 pad -> 2-way conflicts only)
#define SST 65      // LDS score row stride (floats): bank = (r + 16s + c) % 32 -> 2-way

typedef __attribute__((ext_vector_type(8))) short short8;     // 8 bf16 (4 VGPRs)
typedef __attribute__((ext_vector_type(4))) float floatx4;    // MFMA C/D

__device__ __forceinline__ unsigned short f2bf(float f) {
  unsigned int u = __float_as_uint(f);
  return (unsigned short)((u + 0x7fffu + ((u >> 16) & 1u)) >> 16);  // RNE
}

// ---------------- K0: target norms (bit-identical to round-1) + bf16 cast ----------------
__global__ void tn_cast_kernel(const float* __restrict__ tf, float* __restrict__ tn,
                               unsigned short* __restrict__ tfb) {
  int gid = blockIdx.x * blockDim.x + threadIdx.x;
  int w = gid >> 6;
  int lane = gid & 63;
  if (w >= TT) return;
  const float* p = tf + w * FE;
  float a = p[lane];
  float b = p[lane + 64];
  float s = a * a + b * b;
#pragma unroll
  for (int off = 32; off > 0; off >>= 1) s += __shfl_xor(s, off);
  if (lane == 0) tn[w] = s;
  // cast this row to bf16 (coalesced ushort2 per lane)
  float c0 = p[2 * lane], c1 = p[2 * lane + 1];
  ushort2 o;
  o.x = f2bf(c0);
  o.y = f2bf(c1);
  *reinterpret_cast<ushort2*>(tfb + (size_t)w * FE + 2 * lane) = o;
}

// ---------------- K1: bf16-MFMA GEMM + approx top-8/thread + exact rescore ----------------
union SmemU {
  struct {
    unsigned short a[BRR * AST];   // 17408 B
    unsigned short b[BTT * AST];   // 17408 B
    float sc[BRR * SST];           // 16640 B
    float tnl[BTT];                //   256 B
  } p1;
  struct {
    int   ci[BRR][32];             // candidate indices
    float cv[BRR][32];             // rescored exact values
  } p2;
};

__global__ __launch_bounds__(256) void topk_mfma_kernel(
    const float* __restrict__ sf, const float* __restrict__ tf,
    const unsigned short* __restrict__ tfb, const float* __restrict__ tn,
    const float* __restrict__ tp, float* __restrict__ pred) {
  __shared__ SmemU u;
  const int tid = threadIdx.x;
  const int row0 = blockIdx.x * BRR;
  const int lane = tid & 63;
  const int wv = tid >> 6;
  const int rh = wv >> 1;          // row half (0/1)
  const int ch = wv & 1;           // col half (0/1)
  const int q = lane >> 4;         // quadrant
  const int m = lane & 15;

  // ---- stage A: fp32 -> bf16 convert into LDS (once per block) ----
  {
    int rr = tid >> 4;             // 0..15
    int k0 = (tid & 15) << 3;      // 0..120
#pragma unroll
    for (int p = 0; p < 4; ++p) {
      int r = p * 16 + rr;
      int g = row0 + r;
      union { unsigned short us[8]; uint4 v; } t;
      if (g < NS) {
        const float* src = sf + (size_t)g * FE + k0;
        float4 f0 = *reinterpret_cast<const float4*>(src);
        float4 f1 = *reinterpret_cast<const float4*>(src + 4);
        t.us[0] = f2bf(f0.x); t.us[1] = f2bf(f0.y);
        t.us[2] = f2bf(f0.z); t.us[3] = f2bf(f0.w);
        t.us[4] = f2bf(f1.x); t.us[5] = f2bf(f1.y);
        t.us[6] = f2bf(f1.z); t.us[7] = f2bf(f1.w);
      } else {
        t.v = make_uint4(0, 0, 0, 0);
      }
      *reinterpret_cast<uint4*>(&u.p1.a[r * AST + k0]) = t.v;
    }
  }

  float bd[8];
  int   bi[8];
#pragma unroll
  for (int k = 0; k < 8; ++k) { bd[k] = 1e30f; bi[k] = 0; }

  const int sr = tid >> 2;         // scan row 0..63
  const int ss = tid & 3;          // scan col-group 0..3

  for (int t0 = 0; t0 < TT; t0 += BTT) {
    __syncthreads();
    // ---- stage B strip (bf16, pre-converted) ----
    {
      int rr = tid >> 4;
      int k0 = (tid & 15) << 3;
#pragma unroll
      for (int p = 0; p < 4; ++p) {
        int c = p * 16 + rr;
        int gc = t0 + c;
        uint4 v = make_uint4(0, 0, 0, 0);
        if (gc < TT) v = *reinterpret_cast<const uint4*>(tfb + (size_t)gc * FE + k0);
        *reinterpret_cast<uint4*>(&u.p1.b[c * AST + k0]) = v;
      }
    }
    if (tid < BTT) {
      int gc = t0 + tid;
      u.p1.tnl[tid] = (gc < TT) ? tn[gc] : 1e30f;
    }
    __syncthreads();

    // ---- MFMA: wave computes 32x32 as 2x2 frags of 16x16x32, K=128 ----
    floatx4 acc[2][2];
#pragma unroll
    for (int i = 0; i < 2; ++i)
#pragma unroll
      for (int j = 0; j < 2; ++j) acc[i][j] = (floatx4){0.f, 0.f, 0.f, 0.f};

#pragma unroll
    for (int ks = 0; ks < 4; ++ks) {
      int ka = ks * 32 + q * 8;
      short8 a0 = *reinterpret_cast<const short8*>(&u.p1.a[(rh * 32 + m) * AST + ka]);
      short8 a1 = *reinterpret_cast<const short8*>(&u.p1.a[(rh * 32 + 16 + m) * AST + ka]);
      short8 b0 = *reinterpret_cast<const short8*>(&u.p1.b[(ch * 32 + m) * AST + ka]);
      short8 b1 = *reinterpret_cast<const short8*>(&u.p1.b[(ch * 32 + 16 + m) * AST + ka]);
      acc[0][0] = __builtin_amdgcn_mfma_f32_16x16x32_bf16(a0, b0, acc[0][0], 0, 0, 0);
      acc[0][1] = __builtin_amdgcn_mfma_f32_16x16x32_bf16(a0, b1, acc[0][1], 0, 0, 0);
      acc[1][0] = __builtin_amdgcn_mfma_f32_16x16x32_bf16(a1, b0, acc[1][0], 0, 0, 0);
      acc[1][1] = __builtin_amdgcn_mfma_f32_16x16x32_bf16(a1, b1, acc[1][1], 0, 0, 0);
    }

    // ---- scores -> LDS (C layout: row = q*4+reg, col = m) ----
#pragma unroll
    for (int rf = 0; rf < 2; ++rf)
#pragma unroll
      for (int cf = 0; cf < 2; ++cf) {
        int ct = ch * 32 + cf * 16 + m;
        float tl = u.p1.tnl[ct];
#pragma unroll
        for (int reg = 0; reg < 4; ++reg) {
          int rt = rh * 32 + rf * 16 + q * 4 + reg;
          u.p1.sc[rt * SST + ct] = tl - 2.f * acc[rf][cf][reg];
        }
      }
    __syncthreads();

    // ---- approx top-8 scan: 4 threads/row, 16 cols each ----
    {
      const float* srow = &u.p1.sc[sr * SST + ss * 16];
      int cbase = t0 + ss * 16;
#pragma unroll
      for (int j = 0; j < 16; ++j) {
        float v = srow[j];
        if (v < bd[7]) {
          bd[7] = v; bi[7] = cbase + j;
#pragma unroll
          for (int k = 6; k >= 0; --k) {
            if (bd[k + 1] < bd[k]) {
              float tv = bd[k]; bd[k] = bd[k + 1]; bd[k + 1] = tv;
              int ti = bi[k]; bi[k] = bi[k + 1]; bi[k + 1] = ti;
            }
          }
        }
      }
    }
  }

  __syncthreads();
  // dump candidate indices (overlay: all p1 reads are complete)
#pragma unroll
  for (int k = 0; k < 8; ++k) u.p2.ci[sr][ss * 8 + k] = bi[k];
  __syncthreads();

  // ---- exact fp32 rescore (same summation order as the validated fp32 kernel) ----
  {
    int g = row0 + sr;
    if (g < NS) {
      const float* srow = sf + (size_t)g * FE;
#pragma unroll
      for (int k = 0; k < 8; ++k) {
        int c = u.p2.ci[sr][ss * 8 + k];
        const float* trow = tf + (size_t)c * FE;
        float accv = 0.f;
#pragma unroll 8
        for (int kk = 0; kk < FE; kk += 4) {
          float4 av = *reinterpret_cast<const float4*>(srow + kk);
          float4 bv = *reinterpret_cast<const float4*>(trow + kk);
          accv += av.x * bv.x + av.y * bv.y + av.z * bv.z + av.w * bv.w;
        }
        u.p2.cv[sr][ss * 8 + k] = tn[c] - 2.f * accv;
      }
    }
  }
  __syncthreads();

  // ---- exact top-6 of 32 candidates, softmax, gather ----
  if ((tid & 3) == 0) {
    int r = tid >> 2;
    int g = row0 + r;
    if (g < NS) {
      float sd[6]; int sp6[6];
#pragma unroll
      for (int k = 0; k < 6; ++k) { sd[k] = 1e30f; sp6[k] = 0; }
      for (int mm = 0; mm < 32; ++mm) {
        float v = u.p2.cv[r][mm];
        if (v < sd[5]) {
          sd[5] = v; sp6[5] = mm;
#pragma unroll
          for (int k = 4; k >= 0; --k) {
            if (sd[k + 1] < sd[k]) {
              float tv = sd[k]; sd[k] = sd[k + 1]; sd[k + 1] = tv;
              int ti = sp6[k]; sp6[k] = sp6[k + 1]; sp6[k + 1] = ti;
            }
          }
        }
      }
      float w[6]; float wsum = 0.f;
#pragma unroll
      for (int k = 0; k < 6; ++k) { w[k] = __expf(sd[0] - sd[k]); wsum += w[k]; }
      float inv = 1.f / wsum;
      float px = 0.f, py = 0.f, pz = 0.f;
#pragma unroll
      for (int k = 0; k < 6; ++k) {
        float s = w[k] * inv;
        const float* qq = tp + (size_t)u.p2.ci[r][sp6[k]] * 3;
        px += s * qq[0]; py += s * qq[1]; pz += s * qq[2];
      }
      pred[g * 3 + 0] = px;
      pred[g * 3 + 1] = py;
      pred[g * 3 + 2] = pz;
    }
  }
}

// ---------------- K2: per-node Procrustes (3x3 SVD, fp64 Jacobi) ----------------
__global__ __launch_bounds__(256) void proc_kernel(
    const int* __restrict__ colp, const float* __restrict__ pos,
    const float* __restrict__ pred, float* __restrict__ Rout,
    float* __restrict__ tout, float* __restrict__ qnorm) {
  int i = blockIdx.x * blockDim.x + threadIdx.x;
  if (i >= NS) return;
  double sp[3] = {0, 0, 0}, sq[3] = {0, 0, 0};
  double spq[3][3] = {{0, 0, 0}, {0, 0, 0}, {0, 0, 0}};
  const int* ci = colp + i * DEG;
  for (int e = 0; e < DEG; ++e) {
    int c = ci[e];
    double p0 = pos[c * 3], p1 = pos[c * 3 + 1], p2 = pos[c * 3 + 2];
    double q0 = pred[c * 3], q1 = pred[c * 3 + 1], q2 = pred[c * 3 + 2];
    sp[0] += p0; sp[1] += p1; sp[2] += p2;
    sq[0] += q0; sq[1] += q1; sq[2] += q2;
    spq[0][0] += p0 * q0; spq[0][1] += p0 * q1; spq[0][2] += p0 * q2;
    spq[1][0] += p1 * q0; spq[1][1] += p1 * q1; spq[1][2] += p1 * q2;
    spq[2][0] += p2 * q0; spq[2][1] += p2 * q1; spq[2][2] += p2 * q2;
  }
  const double inv = 1.0 / 32.0;
  double A[3][3], sc[3], tcn[3];
  for (int a = 0; a < 3; ++a) {
    sc[a] = sp[a] * inv;
    tcn[a] = sq[a] * inv;
  }
  for (int a = 0; a < 3; ++a)
    for (int b = 0; b < 3; ++b) A[a][b] = spq[a][b] - sp[a] * sq[b] * inv;

  double S[3][3];
  for (int a = 0; a < 3; ++a)
    for (int b = 0; b < 3; ++b)
      S[a][b] = A[0][a] * A[0][b] + A[1][a] * A[1][b] + A[2][a] * A[2][b];
  double V[3][3] = {{1, 0, 0}, {0, 1, 0}, {0, 0, 1}};
  const int JP[3] = {0, 0, 1}, JQ[3] = {1, 2, 2};
  for (int sweep = 0; sweep < 10; ++sweep) {
    for (int r = 0; r < 3; ++r) {
      int p = JP[r], q = JQ[r];
      double apq = S[p][q];
      if (fabs(apq) < 1e-300) continue;
      double theta = (S[q][q] - S[p][p]) / (2.0 * apq);
      double t = copysign(1.0 / (fabs(theta) + sqrt(theta * theta + 1.0)), theta);
      double c = 1.0 / sqrt(t * t + 1.0);
      double s = t * c;
      double spp = S[p][p], sqq = S[q][q];
      S[p][p] = spp - t * apq;
      S[q][q] = sqq + t * apq;
      S[p][q] = 0.0; S[q][p] = 0.0;
      int k = 3 - p - q;
      double skp = S[k][p], skq = S[k][q];
      S[k][p] = S[p][k] = c * skp - s * skq;
      S[k][q] = S[q][k] = s * skp + c * skq;
      for (int mth = 0; mth < 3; ++mth) {
        double vp = V[mth][p], vq = V[mth][q];
        V[mth][p] = c * vp - s * vq;
        V[mth][q] = s * vp + c * vq;
      }
    }
  }
  double lam[3] = {S[0][0], S[1][1], S[2][2]};
  int i0 = 0, i1 = 1, i2 = 2, tmp;
  if (lam[i0] < lam[i1]) { tmp = i0; i0 = i1; i1 = tmp; }
  if (lam[i0] < lam[i2]) { tmp = i0; i0 = i2; i2 = tmp; }
  if (lam[i1] < lam[i2]) { tmp = i1; i1 = i2; i2 = tmp; }
  double v0[3] = {V[0][i0], V[1][i0], V[2][i0]};
  double v1[3] = {V[0][i1], V[1][i1], V[2][i1]};
  double v2[3] = {V[0][i2], V[1][i2], V[2][i2]};

  double Av0[3], Av1[3], Av2[3];
  for (int a = 0; a < 3; ++a) {
    Av0[a] = A[a][0] * v0[0] + A[a][1] * v0[1] + A[a][2] * v0[2];
    Av1[a] = A[a][0] * v1[0] + A[a][1] * v1[1] + A[a][2] * v1[2];
    Av2[a] = A[a][0] * v2[0] + A[a][1] * v2[1] + A[a][2] * v2[2];
  }
  double n0 = fmax(sqrt(Av0[0]*Av0[0] + Av0[1]*Av0[1] + Av0[2]*Av0[2]), 1e-300);
  double u0[3] = {Av0[0] / n0, Av0[1] / n0, Av0[2] / n0};
  double proj = u0[0]*Av1[0] + u0[1]*Av1[1] + u0[2]*Av1[2];
  double u1[3] = {Av1[0] - proj * u0[0], Av1[1] - proj * u0[1], Av1[2] - proj * u0[2]};
  double n1 = fmax(sqrt(u1[0]*u1[0] + u1[1]*u1[1] + u1[2]*u1[2]), 1e-300);
  u1[0] /= n1; u1[1] /= n1; u1[2] /= n1;
  double w[3] = {u0[1]*u1[2] - u0[2]*u1[1],
                 u0[2]*u1[0] - u0[0]*u1[2],
                 u0[0]*u1[1] - u0[1]*u1[0]};
  double dotw = Av2[0]*w[0] + Av2[1]*w[1] + Av2[2]*w[2];
  double sgn = (dotw < 0.0) ? -1.0 : 1.0;
  double detA = A[0][0]*(A[1][1]*A[2][2] - A[1][2]*A[2][1])
              - A[0][1]*(A[1][0]*A[2][2] - A[1][2]*A[2][0])
              + A[0][2]*(A[1][0]*A[2][1] - A[1][1]*A[2][0]);
  double d3 = ((detA < 0.0) ? -1.0 : 1.0) * sgn;

  double R[3][3];
  for (int a = 0; a < 3; ++a)
    for (int b = 0; b < 3; ++b)
      R[a][b] = u0[a]*v0[b] + u1[a]*v1[b] + d3 * w[a]*v2[b];

  for (int a = 0; a < 3; ++a)
    for (int b = 0; b < 3; ++b) Rout[i * 9 + a * 3 + b] = (float)R[a][b];
  double tr_[3];
  for (int a = 0; a < 3; ++a) {
    tr_[a] = tcn[a] - (R[a][0]*sc[0] + R[a][1]*sc[1] + R[a][2]*sc[2]);
    tout[i * 3 + a] = (float)tr_[a];
  }
  double pxi = pos[i * 3], pyi = pos[i * 3 + 1], pzi = pos[i * 3 + 2];
  double r0 = R[0][0]*pxi + R[0][1]*pyi + R[0][2]*pzi + tr_[0] - pred[i * 3];
  double r1 = R[1][0]*pxi + R[1][1]*pyi + R[1][2]*pzi + tr_[1] - pred[i * 3 + 1];
  double r2 = R[2][0]*pxi + R[2][1]*pyi + R[2][2]*pzi + tr_[2] - pred[i * 3 + 2];
  qnorm[i] = (float)(r0 * r0 + r1 * r1 + r2 * r2);
}

// ---------------- K3: per-node residual mean over neighbors ----------------
__global__ __launch_bounds__(256) void dst_kernel(
    const int* __restrict__ colp, const float* __restrict__ qn,
    float* __restrict__ dout) {
  int i = blockIdx.x * blockDim.x + threadIdx.x;
  if (i >= NS) return;
  const int* ci = colp + i * DEG;
  float s = 0.f;
#pragma unroll
  for (int e = 0; e < DEG; ++e) s += qn[ci[e]];
  dout[i] = s * (1.0f / 32.0f);
}

extern "C" void kernel_launch(void* const* d_in, const int* in_sizes, int n_in,
                              void* d_out, int out_size, void* d_ws, size_t ws_size,
                              hipStream_t stream) {
  const float* sf  = (const float*)d_in[0];   // [N,128]
  const float* tf  = (const float*)d_in[1];   // [T,128]
  const float* tp  = (const float*)d_in[2];   // [T,3]
  const float* pos = (const float*)d_in[3];   // [N,3]
  const int*   ei  = (const int*)d_in[4];     // [2,E]
  float* out = (float*)d_out;                 // [N*9 | N*3 | N]
  char* ws = (char*)d_ws;
  // ws layout (needs ~2.02 MB):
  float*          tn   = (float*)(ws);                       // TT floats
  unsigned short* tfb  = (unsigned short*)(ws + 32768);      // TT*128 bf16
  float*          pred = (float*)(ws + 1796608);             // NS*3 floats
  float*          qn   = (float*)(ws + 2036608);             // NS floats
  const int* colp = ei + EDG;

  tn_cast_kernel<<<(TT * 64 + 255) / 256, 256, 0, stream>>>(tf, tn, tfb);
  topk_mfma_kernel<<<(NS + BRR - 1) / BRR, 256, 0, stream>>>(sf, tf, tfb, tn, tp, pred);
  proc_kernel<<<(NS + 255) / 256, 256, 0, stream>>>(colp, pos, pred, out,
                                                    out + NS * 9, qn);
  dst_kernel<<<(NS + 255) / 256, 256, 0, stream>>>(colp, qn, out + NS * 12);
}

// Round 3
// 397.618 us; speedup vs baseline: 3.3949x; 1.9731x over previous
//
#include <hip/hip_runtime.h>
#include <math.h>

#define NS 20000
#define TT 6890
#define TPAD 6912
#define FE 128
#define EDG 640000
#define DEG 32
#define CHUNKS 4
#define SPC 54            // strips of 32 cols per chunk; 4*54*32 = 6912

typedef __attribute__((ext_vector_type(8))) short short8;     // 8 bf16
typedef __attribute__((ext_vector_type(4))) float floatx4;    // MFMA C/D

__device__ __forceinline__ unsigned short f2bf(float f) {
  unsigned int u = __float_as_uint(f);
  return (unsigned short)((u + 0x7fffu + ((u >> 16) & 1u)) >> 16);  // RNE
}

// ---------------- K0: target norms + bf16 cast, padded to TPAD rows ----------------
__global__ void tn_cast_kernel(const float* __restrict__ tf, float* __restrict__ tn,
                               unsigned short* __restrict__ tfb) {
  int gid = blockIdx.x * blockDim.x + threadIdx.x;
  int w = gid >> 6;
  int lane = gid & 63;
  if (w >= TPAD) return;
  if (w < TT) {
    const float* p = tf + (size_t)w * FE;
    float a = p[lane];
    float b = p[lane + 64];
    float s = a * a + b * b;
#pragma unroll
    for (int off = 32; off > 0; off >>= 1) s += __shfl_xor(s, off);
    if (lane == 0) tn[w] = s;
    float c0 = p[2 * lane], c1 = p[2 * lane + 1];
    ushort2 o;
    o.x = f2bf(c0);
    o.y = f2bf(c1);
    *reinterpret_cast<ushort2*>(tfb + (size_t)w * FE + 2 * lane) = o;
  } else {
    if (lane == 0) tn[w] = 1e30f;   // pad cols: metric = -1e30, never selected
    ushort2 z; z.x = 0; z.y = 0;
    *reinterpret_cast<ushort2*>(tfb + (size_t)w * FE + 2 * lane) = z;
  }
}

// ---------------- K1: wave-autonomous MFMA + register top-k ----------------
// Wave = 32 source rows x one T-chunk. MFMA orientation: A = target strip
// (D-row = tcol), B = source rows (D-col = srow) -> each lane's outputs span
// only srows {m, m+16}: candidate lists live in registers, zero LDS in loop.
__global__ __launch_bounds__(256, 3) void topk_wave_kernel(
    const float* __restrict__ sf, const float* __restrict__ tf,
    const unsigned short* __restrict__ tfb, const float* __restrict__ tn,
    const float* __restrict__ tp, float* __restrict__ pred) {
  __shared__ float lmet[32][CHUNKS][33];   // [row][chunk][lane-slot], +1 pad
  __shared__ int   lidx[32][CHUNKS][33];
  __shared__ int   pidx[32][33];           // pruned 32 candidates per row
  __shared__ float pval[32][33];           // fp32 rescored values

  const int tid = threadIdx.x;
  const int lane = tid & 63;
  const int wv = tid >> 6;                 // T-chunk id 0..3
  const int q = lane >> 4;
  const int m = lane & 15;
  const int srow0 = blockIdx.x * 32;

  // resident B-operand fragments: sf rows {srow0+h*16+m}, bf16
  short8 bfr[2][4];
#pragma unroll
  for (int h = 0; h < 2; ++h) {
    const float* src = sf + (size_t)(srow0 + h * 16 + m) * FE;
#pragma unroll
    for (int ks = 0; ks < 4; ++ks) {
      float4 f0 = *reinterpret_cast<const float4*>(src + ks * 32 + q * 8);
      float4 f1 = *reinterpret_cast<const float4*>(src + ks * 32 + q * 8 + 4);
      union { unsigned short us[8]; short8 s8; } t;
      t.us[0] = f2bf(f0.x); t.us[1] = f2bf(f0.y);
      t.us[2] = f2bf(f0.z); t.us[3] = f2bf(f0.w);
      t.us[4] = f2bf(f1.x); t.us[5] = f2bf(f1.y);
      t.us[6] = f2bf(f1.z); t.us[7] = f2bf(f1.w);
      bfr[h][ks] = t.s8;
    }
  }

  float bd[2][8];                          // maximize metric = 2*dot - tn
  int   bi[2][8];
#pragma unroll
  for (int h = 0; h < 2; ++h)
#pragma unroll
    for (int k = 0; k < 8; ++k) { bd[h][k] = -3e38f; bi[h][k] = 0; }

  const int colbase = wv * (SPC * 32);
  for (int s = 0; s < SPC; ++s) {
    const int tcol0 = colbase + s * 32;
    // A-operand fragments straight from L2 (no LDS)
    short8 af[2][4];
#pragma unroll
    for (int a = 0; a < 2; ++a) {
      const unsigned short* base = tfb + (size_t)(tcol0 + a * 16 + m) * FE;
#pragma unroll
      for (int ks = 0; ks < 4; ++ks)
        af[a][ks] = *reinterpret_cast<const short8*>(base + ks * 32 + q * 8);
    }
    float4 t40 = *reinterpret_cast<const float4*>(tn + tcol0 + q * 4);
    float4 t41 = *reinterpret_cast<const float4*>(tn + tcol0 + 16 + q * 4);

    floatx4 acc[2][2];
#pragma unroll
    for (int a = 0; a < 2; ++a)
#pragma unroll
      for (int h = 0; h < 2; ++h) acc[a][h] = (floatx4){0.f, 0.f, 0.f, 0.f};
#pragma unroll
    for (int ks = 0; ks < 4; ++ks) {
      acc[0][0] = __builtin_amdgcn_mfma_f32_16x16x32_bf16(af[0][ks], bfr[0][ks], acc[0][0], 0, 0, 0);
      acc[0][1] = __builtin_amdgcn_mfma_f32_16x16x32_bf16(af[0][ks], bfr[1][ks], acc[0][1], 0, 0, 0);
      acc[1][0] = __builtin_amdgcn_mfma_f32_16x16x32_bf16(af[1][ks], bfr[0][ks], acc[1][0], 0, 0, 0);
      acc[1][1] = __builtin_amdgcn_mfma_f32_16x16x32_bf16(af[1][ks], bfr[1][ks], acc[1][1], 0, 0, 0);
    }

    float tv0[4] = {t40.x, t40.y, t40.z, t40.w};
    float tv1[4] = {t41.x, t41.y, t41.z, t41.w};
#pragma unroll
    for (int a = 0; a < 2; ++a) {
#pragma unroll
      for (int r = 0; r < 4; ++r) {
        float tnv = a ? tv1[r] : tv0[r];
        int c = tcol0 + a * 16 + q * 4 + r;   // D-row = tcol
#pragma unroll
        for (int h = 0; h < 2; ++h) {
          float v = 2.f * acc[a][h][r] - tnv;
          if (v > bd[h][7]) {
            bd[h][7] = v; bi[h][7] = c;
#pragma unroll
            for (int k = 6; k >= 0; --k) {
              if (bd[h][k + 1] > bd[h][k]) {
                float tvv = bd[h][k]; bd[h][k] = bd[h][k + 1]; bd[h][k + 1] = tvv;
                int tii = bi[h][k]; bi[h][k] = bi[h][k + 1]; bi[h][k + 1] = tii;
              }
            }
          }
        }
      }
    }
  }

  // dump per-lane candidates (once per kernel)
#pragma unroll
  for (int h = 0; h < 2; ++h)
#pragma unroll
    for (int k = 0; k < 8; ++k) {
      lmet[h * 16 + m][wv][q * 8 + k] = bd[h][k];
      lidx[h * 16 + m][wv][q * 8 + k] = bi[h][k];
    }
  __syncthreads();

  // prune: per (row, chunk) top-8 of 32 -> union 32/row (same guarantee as R2)
  if (tid < 128) {
    int r = tid >> 2, c = tid & 3;
    float md[8]; int mi[8];
#pragma unroll
    for (int k = 0; k < 8; ++k) { md[k] = -3e38f; mi[k] = 0; }
    for (int j = 0; j < 32; ++j) {
      float v = lmet[r][c][j];
      int ci = lidx[r][c][j];
      if (v > md[7]) {
        md[7] = v; mi[7] = ci;
#pragma unroll
        for (int k = 6; k >= 0; --k)
          if (md[k + 1] > md[k]) {
            float tvv = md[k]; md[k] = md[k + 1]; md[k + 1] = tvv;
            int tii = mi[k]; mi[k] = mi[k + 1]; mi[k + 1] = tii;
          }
      }
    }
#pragma unroll
    for (int k = 0; k < 8; ++k) pidx[r][c * 8 + k] = mi[k];
  }
  __syncthreads();

  // fp32 rescore, exact round-2 arithmetic (8 threads/row x 4 cands)
  {
    int r = tid >> 3, p = tid & 7;
    const float* srow = sf + (size_t)(srow0 + r) * FE;
#pragma unroll
    for (int k = 0; k < 4; ++k) {
      int c = pidx[r][p * 4 + k];
      const float* trow = tf + (size_t)c * FE;
      float accv = 0.f;
#pragma unroll 8
      for (int kk = 0; kk < FE; kk += 4) {
        float4 av = *reinterpret_cast<const float4*>(srow + kk);
        float4 bv = *reinterpret_cast<const float4*>(trow + kk);
        accv += av.x * bv.x + av.y * bv.y + av.z * bv.z + av.w * bv.w;
      }
      pval[r][p * 4 + k] = tn[c] - 2.f * accv;
    }
  }
  __syncthreads();

  // exact top-6 of 32, softmax, gather
  if (tid < 32) {
    int g = srow0 + tid;
    float sd[6]; int sp6[6];
#pragma unroll
    for (int k = 0; k < 6; ++k) { sd[k] = 1e30f; sp6[k] = 0; }
    for (int j = 0; j < 32; ++j) {
      float v = pval[tid][j];
      if (v < sd[5]) {
        sd[5] = v; sp6[5] = j;
#pragma unroll
        for (int k = 4; k >= 0; --k) {
          if (sd[k + 1] < sd[k]) {
            float tvv = sd[k]; sd[k] = sd[k + 1]; sd[k + 1] = tvv;
            int tii = sp6[k]; sp6[k] = sp6[k + 1]; sp6[k + 1] = tii;
          }
        }
      }
    }
    float w[6]; float wsum = 0.f;
#pragma unroll
    for (int k = 0; k < 6; ++k) { w[k] = __expf(sd[0] - sd[k]); wsum += w[k]; }
    float inv = 1.f / wsum;
    float px = 0.f, py = 0.f, pz = 0.f;
#pragma unroll
    for (int k = 0; k < 6; ++k) {
      float sc = w[k] * inv;
      const float* qq = tp + (size_t)pidx[tid][sp6[k]] * 3;
      px += sc * qq[0]; py += sc * qq[1]; pz += sc * qq[2];
    }
    pred[g * 3 + 0] = px;
    pred[g * 3 + 1] = py;
    pred[g * 3 + 2] = pz;
  }
}

// ---------------- K2: per-node Procrustes (3x3 SVD, fp64 Jacobi) ----------------
__global__ __launch_bounds__(256) void proc_kernel(
    const int* __restrict__ colp, const float* __restrict__ pos,
    const float* __restrict__ pred, float* __restrict__ Rout,
    float* __restrict__ tout, float* __restrict__ qnorm) {
  int i = blockIdx.x * blockDim.x + threadIdx.x;
  if (i >= NS) return;
  double sp[3] = {0, 0, 0}, sq[3] = {0, 0, 0};
  double spq[3][3] = {{0, 0, 0}, {0, 0, 0}, {0, 0, 0}};
  const int* ci = colp + i * DEG;
  for (int e = 0; e < DEG; ++e) {
    int c = ci[e];
    double p0 = pos[c * 3], p1 = pos[c * 3 + 1], p2 = pos[c * 3 + 2];
    double q0 = pred[c * 3], q1 = pred[c * 3 + 1], q2 = pred[c * 3 + 2];
    sp[0] += p0; sp[1] += p1; sp[2] += p2;
    sq[0] += q0; sq[1] += q1; sq[2] += q2;
    spq[0][0] += p0 * q0; spq[0][1] += p0 * q1; spq[0][2] += p0 * q2;
    spq[1][0] += p1 * q0; spq[1][1] += p1 * q1; spq[1][2] += p1 * q2;
    spq[2][0] += p2 * q0; spq[2][1] += p2 * q1; spq[2][2] += p2 * q2;
  }
  const double inv = 1.0 / 32.0;
  double A[3][3], sc[3], tcn[3];
  for (int a = 0; a < 3; ++a) {
    sc[a] = sp[a] * inv;
    tcn[a] = sq[a] * inv;
  }
  for (int a = 0; a < 3; ++a)
    for (int b = 0; b < 3; ++b) A[a][b] = spq[a][b] - sp[a] * sq[b] * inv;

  double S[3][3];
  for (int a = 0; a < 3; ++a)
    for (int b = 0; b < 3; ++b)
      S[a][b] = A[0][a] * A[0][b] + A[1][a] * A[1][b] + A[2][a] * A[2][b];
  double V[3][3] = {{1, 0, 0}, {0, 1, 0}, {0, 0, 1}};
  const int JP[3] = {0, 0, 1}, JQ[3] = {1, 2, 2};
  for (int sweep = 0; sweep < 10; ++sweep) {
    for (int r = 0; r < 3; ++r) {
      int p = JP[r], q = JQ[r];
      double apq = S[p][q];
      if (fabs(apq) < 1e-300) continue;
      double theta = (S[q][q] - S[p][p]) / (2.0 * apq);
      double t = copysign(1.0 / (fabs(theta) + sqrt(theta * theta + 1.0)), theta);
      double c = 1.0 / sqrt(t * t + 1.0);
      double s = t * c;
      double spp = S[p][p], sqq = S[q][q];
      S[p][p] = spp - t * apq;
      S[q][q] = sqq + t * apq;
      S[p][q] = 0.0; S[q][p] = 0.0;
      int k = 3 - p - q;
      double skp = S[k][p], skq = S[k][q];
      S[k][p] = S[p][k] = c * skp - s * skq;
      S[k][q] = S[q][k] = s * skp + c * skq;
      for (int mth = 0; mth < 3; ++mth) {
        double vp = V[mth][p], vq = V[mth][q];
        V[mth][p] = c * vp - s * vq;
        V[mth][q] = s * vp + c * vq;
      }
    }
  }
  double lam[3] = {S[0][0], S[1][1], S[2][2]};
  int i0 = 0, i1 = 1, i2 = 2, tmp;
  if (lam[i0] < lam[i1]) { tmp = i0; i0 = i1; i1 = tmp; }
  if (lam[i0] < lam[i2]) { tmp = i0; i0 = i2; i2 = tmp; }
  if (lam[i1] < lam[i2]) { tmp = i1; i1 = i2; i2 = tmp; }
  double v0[3] = {V[0][i0], V[1][i0], V[2][i0]};
  double v1[3] = {V[0][i1], V[1][i1], V[2][i1]};
  double v2[3] = {V[0][i2], V[1][i2], V[2][i2]};

  double Av0[3], Av1[3], Av2[3];
  for (int a = 0; a < 3; ++a) {
    Av0[a] = A[a][0] * v0[0] + A[a][1] * v0[1] + A[a][2] * v0[2];
    Av1[a] = A[a][0] * v1[0] + A[a][1] * v1[1] + A[a][2] * v1[2];
    Av2[a] = A[a][0] * v2[0] + A[a][1] * v2[1] + A[a][2] * v2[2];
  }
  double n0 = fmax(sqrt(Av0[0]*Av0[0] + Av0[1]*Av0[1] + Av0[2]*Av0[2]), 1e-300);
  double u0[3] = {Av0[0] / n0, Av0[1] / n0, Av0[2] / n0};
  double proj = u0[0]*Av1[0] + u0[1]*Av1[1] + u0[2]*Av1[2];
  double u1[3] = {Av1[0] - proj * u0[0], Av1[1] - proj * u0[1], Av1[2] - proj * u0[2]};
  double n1 = fmax(sqrt(u1[0]*u1[0] + u1[1]*u1[1] + u1[2]*u1[2]), 1e-300);
  u1[0] /= n1; u1[1] /= n1; u1[2] /= n1;
  double w[3] = {u0[1]*u1[2] - u0[2]*u1[1],
                 u0[2]*u1[0] - u0[0]*u1[2],
                 u0[0]*u1[1] - u0[1]*u1[0]};
  double dotw = Av2[0]*w[0] + Av2[1]*w[1] + Av2[2]*w[2];
  double sgn = (dotw < 0.0) ? -1.0 : 1.0;
  double detA = A[0][0]*(A[1][1]*A[2][2] - A[1][2]*A[2][1])
              - A[0][1]*(A[1][0]*A[2][2] - A[1][2]*A[2][0])
              + A[0][2]*(A[1][0]*A[2][1] - A[1][1]*A[2][0]);
  double d3 = ((detA < 0.0) ? -1.0 : 1.0) * sgn;

  double R[3][3];
  for (int a = 0; a < 3; ++a)
    for (int b = 0; b < 3; ++b)
      R[a][b] = u0[a]*v0[b] + u1[a]*v1[b] + d3 * w[a]*v2[b];

  for (int a = 0; a < 3; ++a)
    for (int b = 0; b < 3; ++b) Rout[i * 9 + a * 3 + b] = (float)R[a][b];
  double tr_[3];
  for (int a = 0; a < 3; ++a) {
    tr_[a] = tcn[a] - (R[a][0]*sc[0] + R[a][1]*sc[1] + R[a][2]*sc[2]);
    tout[i * 3 + a] = (float)tr_[a];
  }
  double pxi = pos[i * 3], pyi = pos[i * 3 + 1], pzi = pos[i * 3 + 2];
  double r0 = R[0][0]*pxi + R[0][1]*pyi + R[0][2]*pzi + tr_[0] - pred[i * 3];
  double r1 = R[1][0]*pxi + R[1][1]*pyi + R[1][2]*pzi + tr_[1] - pred[i * 3 + 1];
  double r2 = R[2][0]*pxi + R[2][1]*pyi + R[2][2]*pzi + tr_[2] - pred[i * 3 + 2];
  qnorm[i] = (float)(r0 * r0 + r1 * r1 + r2 * r2);
}

// ---------------- K3: per-node residual mean over neighbors ----------------
__global__ __launch_bounds__(256) void dst_kernel(
    const int* __restrict__ colp, const float* __restrict__ qn,
    float* __restrict__ dout) {
  int i = blockIdx.x * blockDim.x + threadIdx.x;
  if (i >= NS) return;
  const int* ci = colp + i * DEG;
  float s = 0.f;
#pragma unroll
  for (int e = 0; e < DEG; ++e) s += qn[ci[e]];
  dout[i] = s * (1.0f / 32.0f);
}

extern "C" void kernel_launch(void* const* d_in, const int* in_sizes, int n_in,
                              void* d_out, int out_size, void* d_ws, size_t ws_size,
                              hipStream_t stream) {
  const float* sf  = (const float*)d_in[0];   // [N,128]
  const float* tf  = (const float*)d_in[1];   // [T,128]
  const float* tp  = (const float*)d_in[2];   // [T,3]
  const float* pos = (const float*)d_in[3];   // [N,3]
  const int*   ei  = (const int*)d_in[4];     // [2,E]
  float* out = (float*)d_out;                 // [N*9 | N*3 | N]
  char* ws = (char*)d_ws;
  // ws layout (~2.04 MB; qn aliases tfb which is dead after topk):
  float*          tn   = (float*)(ws);                   // 27,648 B
  float*          pred = (float*)(ws + 28672);           // 240,000 B
  unsigned short* tfb  = (unsigned short*)(ws + 268800); // 1,769,472 B
  float*          qn   = (float*)(ws + 268800);          // alias (post-topk)
  const int* colp = ei + EDG;

  tn_cast_kernel<<<(TPAD * 64) / 256, 256, 0, stream>>>(tf, tn, tfb);
  topk_wave_kernel<<<NS / 32, 256, 0, stream>>>(sf, tf, tfb, tn, tp, pred);
  proc_kernel<<<(NS + 255) / 256, 256, 0, stream>>>(colp, pos, pred, out,
                                                    out + NS * 9, qn);
  dst_kernel<<<(NS + 255) / 256, 256, 0, stream>>>(colp, qn, out + NS * 12);
}

// Round 4
// 367.271 us; speedup vs baseline: 3.6755x; 1.0826x over previous
//
#include <hip/hip_runtime.h>
#include <math.h>

#define NS 20000
#define TT 6890
#define TPAD 6912
#define FE 128
#define EDG 640000
#define DEG 32
#define CH 8              // col-chunks per block (one per wave)
#define SPC 27            // strips of 32 cols per chunk; 8*27*32 = 6912 = TPAD

typedef __attribute__((ext_vector_type(8))) short short8;     // 8 bf16
typedef __attribute__((ext_vector_type(4))) float floatx4;    // MFMA C/D
typedef unsigned int uint;

__device__ __forceinline__ unsigned short f2bf(float f) {
  unsigned int u = __float_as_uint(f);
  return (unsigned short)((u + 0x7fffu + ((u >> 16) & 1u)) >> 16);  // RNE
}

// ---------------- K0: target norms (+biased copy) + bf16 cast, padded ----------------
__global__ void tn_cast_kernel(const float* __restrict__ tf, float* __restrict__ tn,
                               float* __restrict__ tn256,
                               unsigned short* __restrict__ tfb) {
  int gid = blockIdx.x * blockDim.x + threadIdx.x;
  int w = gid >> 6;
  int lane = gid & 63;
  if (w >= TPAD) return;
  if (w < TT) {
    const float* p = tf + (size_t)w * FE;
    float a = p[lane];
    float b = p[lane + 64];
    float s = a * a + b * b;
#pragma unroll
    for (int off = 32; off > 0; off >>= 1) s += __shfl_xor(s, off);
    if (lane == 0) { tn[w] = s; tn256[w] = s + 256.0f; }
    float c0 = p[2 * lane], c1 = p[2 * lane + 1];
    ushort2 o;
    o.x = f2bf(c0);
    o.y = f2bf(c1);
    *reinterpret_cast<ushort2*>(tfb + (size_t)w * FE + 2 * lane) = o;
  } else {
    if (lane == 0) { tn[w] = 1e30f; tn256[w] = 3e38f; }  // pads never selected
    ushort2 z; z.x = 0; z.y = 0;
    *reinterpret_cast<ushort2*>(tfb + (size_t)w * FE + 2 * lane) = z;
  }
}

// ---------------- K1: wave-autonomous MFMA + packed-key branchless top-k ----------------
// Wave = 32 source rows x one T-chunk (A = target strip -> D-row = tcol,
// B = source rows -> D-col = srow). Candidate lists: 6 packed uints per
// (lane, h): key = (bits(met) & ~0x1FFF) | col, met = tn+256-2*dp > 0 so
// uint order == float order. Branchless 12-op bubble insert per element.
__global__ __launch_bounds__(512, 4) void topk_wave_kernel(
    const float* __restrict__ sf, const float* __restrict__ tf,
    const unsigned short* __restrict__ tfb, const float* __restrict__ tn,
    const float* __restrict__ tn256, const float* __restrict__ tp,
    float* __restrict__ pred) {
  __shared__ uint  lk[32][CH][26];   // per-(row,chunk) 4q*6 candidate keys
  __shared__ uint  pk[32][49];       // merged 48 keys per row
  __shared__ float pv[32][49];       // fp32 rescored dists

  const int tid = threadIdx.x;
  const int lane = tid & 63;
  const int wv = tid >> 6;                 // T-chunk id 0..7
  const int q = lane >> 4;
  const int m = lane & 15;
  const int srow0 = blockIdx.x * 32;

  // resident B-operand fragments: sf rows {srow0+h*16+m}, bf16
  short8 bfr[2][4];
#pragma unroll
  for (int h = 0; h < 2; ++h) {
    const float* src = sf + (size_t)(srow0 + h * 16 + m) * FE;
#pragma unroll
    for (int ks = 0; ks < 4; ++ks) {
      float4 f0 = *reinterpret_cast<const float4*>(src + ks * 32 + q * 8);
      float4 f1 = *reinterpret_cast<const float4*>(src + ks * 32 + q * 8 + 4);
      union { unsigned short us[8]; short8 s8; } t;
      t.us[0] = f2bf(f0.x); t.us[1] = f2bf(f0.y);
      t.us[2] = f2bf(f0.z); t.us[3] = f2bf(f0.w);
      t.us[4] = f2bf(f1.x); t.us[5] = f2bf(f1.y);
      t.us[6] = f2bf(f1.z); t.us[7] = f2bf(f1.w);
      bfr[h][ks] = t.s8;
    }
  }

  uint kq[2][6];
#pragma unroll
  for (int h = 0; h < 2; ++h)
#pragma unroll
    for (int k = 0; k < 6; ++k) kq[h][k] = 0xFFFFFFFFu;

  const int colbase = wv * (SPC * 32);
  for (int s = 0; s < SPC; ++s) {
    const int tcol0 = colbase + s * 32;
    short8 af[2][4];
#pragma unroll
    for (int a = 0; a < 2; ++a) {
      const unsigned short* base = tfb + (size_t)(tcol0 + a * 16 + m) * FE;
#pragma unroll
      for (int ks = 0; ks < 4; ++ks)
        af[a][ks] = *reinterpret_cast<const short8*>(base + ks * 32 + q * 8);
    }
    float4 t40 = *reinterpret_cast<const float4*>(tn256 + tcol0 + q * 4);
    float4 t41 = *reinterpret_cast<const float4*>(tn256 + tcol0 + 16 + q * 4);

    floatx4 acc[2][2];
#pragma unroll
    for (int a = 0; a < 2; ++a)
#pragma unroll
      for (int h = 0; h < 2; ++h) acc[a][h] = (floatx4){0.f, 0.f, 0.f, 0.f};
#pragma unroll
    for (int ks = 0; ks < 4; ++ks) {
      acc[0][0] = __builtin_amdgcn_mfma_f32_16x16x32_bf16(af[0][ks], bfr[0][ks], acc[0][0], 0, 0, 0);
      acc[0][1] = __builtin_amdgcn_mfma_f32_16x16x32_bf16(af[0][ks], bfr[1][ks], acc[0][1], 0, 0, 0);
      acc[1][0] = __builtin_amdgcn_mfma_f32_16x16x32_bf16(af[1][ks], bfr[0][ks], acc[1][0], 0, 0, 0);
      acc[1][1] = __builtin_amdgcn_mfma_f32_16x16x32_bf16(af[1][ks], bfr[1][ks], acc[1][1], 0, 0, 0);
    }

    float tv0[4] = {t40.x, t40.y, t40.z, t40.w};
    float tv1[4] = {t41.x, t41.y, t41.z, t41.w};
    const uint cb0 = (uint)(tcol0 + q * 4);
    const uint cb1 = cb0 + 16u;
#pragma unroll
    for (int a = 0; a < 2; ++a) {
      uint cb = a ? cb1 : cb0;
#pragma unroll
      for (int r = 0; r < 4; ++r) {
        float tnv = a ? tv1[r] : tv0[r];
#pragma unroll
        for (int h = 0; h < 2; ++h) {
          float met = fmaf(-2.f, acc[a][h][r], tnv);          // > 0 always
          uint key = ((__float_as_uint(met) & 0xFFFFE000u) | cb) + (uint)r;
          uint t = key;
#pragma unroll
          for (int k = 0; k < 6; ++k) {                        // branchless insert
            uint lo = min(kq[h][k], t);
            uint hi = max(kq[h][k], t);
            kq[h][k] = lo;
            t = hi;
          }
        }
      }
    }
  }

  // dump candidates (once per kernel)
#pragma unroll
  for (int h = 0; h < 2; ++h)
#pragma unroll
    for (int k = 0; k < 6; ++k) lk[h * 16 + m][wv][q * 6 + k] = kq[h][k];
  __syncthreads();

  // merge: per (row, chunk) top-6 of 24 -> 48 candidates/row
  if (tid < 256) {
    int r = tid >> 3, c = tid & 7;
    uint md[6];
#pragma unroll
    for (int k = 0; k < 6; ++k) md[k] = 0xFFFFFFFFu;
    for (int j = 0; j < 24; ++j) {
      uint t = lk[r][c][j];
#pragma unroll
      for (int k = 0; k < 6; ++k) {
        uint lo = min(md[k], t);
        uint hi = max(md[k], t);
        md[k] = lo;
        t = hi;
      }
    }
#pragma unroll
    for (int k = 0; k < 6; ++k) pk[r][c * 6 + k] = md[k];
  }
  __syncthreads();

  // fp32 rescore, exact round-1 arithmetic (16 threads/row x 3 cands)
  {
    int r = tid >> 4, p = tid & 15;
    const float* srow = sf + (size_t)(srow0 + r) * FE;
#pragma unroll
    for (int k = 0; k < 3; ++k) {
      int c = (int)(pk[r][p * 3 + k] & 0x1FFFu);
      const float* trow = tf + (size_t)c * FE;
      float accv = 0.f;
#pragma unroll 8
      for (int kk = 0; kk < FE; kk += 4) {
        float4 av = *reinterpret_cast<const float4*>(srow + kk);
        float4 bv = *reinterpret_cast<const float4*>(trow + kk);
        accv += av.x * bv.x + av.y * bv.y + av.z * bv.z + av.w * bv.w;
      }
      pv[r][p * 3 + k] = tn[c] - 2.f * accv;
    }
  }
  __syncthreads();

  // exact top-6 of 48, softmax, gather
  if (tid < 32) {
    int g = srow0 + tid;
    float sd[6]; int sp6[6];
#pragma unroll
    for (int k = 0; k < 6; ++k) { sd[k] = 1e30f; sp6[k] = 0; }
    for (int j = 0; j < 48; ++j) {
      float v = pv[tid][j];
      if (v < sd[5]) {
        sd[5] = v; sp6[5] = j;
#pragma unroll
        for (int k = 4; k >= 0; --k) {
          if (sd[k + 1] < sd[k]) {
            float tvv = sd[k]; sd[k] = sd[k + 1]; sd[k + 1] = tvv;
            int tii = sp6[k]; sp6[k] = sp6[k + 1]; sp6[k + 1] = tii;
          }
        }
      }
    }
    float w[6]; float wsum = 0.f;
#pragma unroll
    for (int k = 0; k < 6; ++k) { w[k] = __expf(sd[0] - sd[k]); wsum += w[k]; }
    float inv = 1.f / wsum;
    float px = 0.f, py = 0.f, pz = 0.f;
#pragma unroll
    for (int k = 0; k < 6; ++k) {
      float sc = w[k] * inv;
      const float* qq = tp + (size_t)(pk[tid][sp6[k]] & 0x1FFFu) * 3;
      px += sc * qq[0]; py += sc * qq[1]; pz += sc * qq[2];
    }
    pred[g * 3 + 0] = px;
    pred[g * 3 + 1] = py;
    pred[g * 3 + 2] = pz;
  }
}

// ---------------- K2: per-node Procrustes (3x3 SVD, fp64 Jacobi) ----------------
__global__ __launch_bounds__(256) void proc_kernel(
    const int* __restrict__ colp, const float* __restrict__ pos,
    const float* __restrict__ pred, float* __restrict__ Rout,
    float* __restrict__ tout, float* __restrict__ qnorm) {
  int i = blockIdx.x * blockDim.x + threadIdx.x;
  if (i >= NS) return;
  double sp[3] = {0, 0, 0}, sq[3] = {0, 0, 0};
  double spq[3][3] = {{0, 0, 0}, {0, 0, 0}, {0, 0, 0}};
  const int* ci = colp + i * DEG;
  for (int e = 0; e < DEG; ++e) {
    int c = ci[e];
    double p0 = pos[c * 3], p1 = pos[c * 3 + 1], p2 = pos[c * 3 + 2];
    double q0 = pred[c * 3], q1 = pred[c * 3 + 1], q2 = pred[c * 3 + 2];
    sp[0] += p0; sp[1] += p1; sp[2] += p2;
    sq[0] += q0; sq[1] += q1; sq[2] += q2;
    spq[0][0] += p0 * q0; spq[0][1] += p0 * q1; spq[0][2] += p0 * q2;
    spq[1][0] += p1 * q0; spq[1][1] += p1 * q1; spq[1][2] += p1 * q2;
    spq[2][0] += p2 * q0; spq[2][1] += p2 * q1; spq[2][2] += p2 * q2;
  }
  const double inv = 1.0 / 32.0;
  double A[3][3], sc[3], tcn[3];
  for (int a = 0; a < 3; ++a) {
    sc[a] = sp[a] * inv;
    tcn[a] = sq[a] * inv;
  }
  for (int a = 0; a < 3; ++a)
    for (int b = 0; b < 3; ++b) A[a][b] = spq[a][b] - sp[a] * sq[b] * inv;

  double S[3][3];
  for (int a = 0; a < 3; ++a)
    for (int b = 0; b < 3; ++b)
      S[a][b] = A[0][a] * A[0][b] + A[1][a] * A[1][b] + A[2][a] * A[2][b];
  double V[3][3] = {{1, 0, 0}, {0, 1, 0}, {0, 0, 1}};
  const int JP[3] = {0, 0, 1}, JQ[3] = {1, 2, 2};
  for (int sweep = 0; sweep < 6; ++sweep) {
    for (int r = 0; r < 3; ++r) {
      int p = JP[r], q = JQ[r];
      double apq = S[p][q];
      if (fabs(apq) < 1e-300) continue;
      double theta = (S[q][q] - S[p][p]) / (2.0 * apq);
      double t = copysign(1.0 / (fabs(theta) + sqrt(theta * theta + 1.0)), theta);
      double c = 1.0 / sqrt(t * t + 1.0);
      double s = t * c;
      double spp = S[p][p], sqq = S[q][q];
      S[p][p] = spp - t * apq;
      S[q][q] = sqq + t * apq;
      S[p][q] = 0.0; S[q][p] = 0.0;
      int k = 3 - p - q;
      double skp = S[k][p], skq = S[k][q];
      S[k][p] = S[p][k] = c * skp - s * skq;
      S[k][q] = S[q][k] = s * skp + c * skq;
      for (int mth = 0; mth < 3; ++mth) {
        double vp = V[mth][p], vq = V[mth][q];
        V[mth][p] = c * vp - s * vq;
        V[mth][q] = s * vp + c * vq;
      }
    }
  }
  double lam[3] = {S[0][0], S[1][1], S[2][2]};
  int i0 = 0, i1 = 1, i2 = 2, tmp;
  if (lam[i0] < lam[i1]) { tmp = i0; i0 = i1; i1 = tmp; }
  if (lam[i0] < lam[i2]) { tmp = i0; i0 = i2; i2 = tmp; }
  if (lam[i1] < lam[i2]) { tmp = i1; i1 = i2; i2 = tmp; }
  double v0[3] = {V[0][i0], V[1][i0], V[2][i0]};
  double v1[3] = {V[0][i1], V[1][i1], V[2][i1]};
  double v2[3] = {V[0][i2], V[1][i2], V[2][i2]};

  double Av0[3], Av1[3], Av2[3];
  for (int a = 0; a < 3; ++a) {
    Av0[a] = A[a][0] * v0[0] + A[a][1] * v0[1] + A[a][2] * v0[2];
    Av1[a] = A[a][0] * v1[0] + A[a][1] * v1[1] + A[a][2] * v1[2];
    Av2[a] = A[a][0] * v2[0] + A[a][1] * v2[1] + A[a][2] * v2[2];
  }
  double n0 = fmax(sqrt(Av0[0]*Av0[0] + Av0[1]*Av0[1] + Av0[2]*Av0[2]), 1e-300);
  double u0[3] = {Av0[0] / n0, Av0[1] / n0, Av0[2] / n0};
  double proj = u0[0]*Av1[0] + u0[1]*Av1[1] + u0[2]*Av1[2];
  double u1[3] = {Av1[0] - proj * u0[0], Av1[1] - proj * u0[1], Av1[2] - proj * u0[2]};
  double n1 = fmax(sqrt(u1[0]*u1[0] + u1[1]*u1[1] + u1[2]*u1[2]), 1e-300);
  u1[0] /= n1; u1[1] /= n1; u1[2] /= n1;
  double w[3] = {u0[1]*u1[2] - u0[2]*u1[1],
                 u0[2]*u1[0] - u0[0]*u1[2],
                 u0[0]*u1[1] - u0[1]*u1[0]};
  double dotw = Av2[0]*w[0] + Av2[1]*w[1] + Av2[2]*w[2];
  double sgn = (dotw < 0.0) ? -1.0 : 1.0;
  double detA = A[0][0]*(A[1][1]*A[2][2] - A[1][2]*A[2][1])
              - A[0][1]*(A[1][0]*A[2][2] - A[1][2]*A[2][0])
              + A[0][2]*(A[1][0]*A[2][1] - A[1][1]*A[2][0]);
  double d3 = ((detA < 0.0) ? -1.0 : 1.0) * sgn;

  double R[3][3];
  for (int a = 0; a < 3; ++a)
    for (int b = 0; b < 3; ++b)
      R[a][b] = u0[a]*v0[b] + u1[a]*v1[b] + d3 * w[a]*v2[b];

  for (int a = 0; a < 3; ++a)
    for (int b = 0; b < 3; ++b) Rout[i * 9 + a * 3 + b] = (float)R[a][b];
  double tr_[3];
  for (int a = 0; a < 3; ++a) {
    tr_[a] = tcn[a] - (R[a][0]*sc[0] + R[a][1]*sc[1] + R[a][2]*sc[2]);
    tout[i * 3 + a] = (float)tr_[a];
  }
  double pxi = pos[i * 3], pyi = pos[i * 3 + 1], pzi = pos[i * 3 + 2];
  double r0 = R[0][0]*pxi + R[0][1]*pyi + R[0][2]*pzi + tr_[0] - pred[i * 3];
  double r1 = R[1][0]*pxi + R[1][1]*pyi + R[1][2]*pzi + tr_[1] - pred[i * 3 + 1];
  double r2 = R[2][0]*pxi + R[2][1]*pyi + R[2][2]*pzi + tr_[2] - pred[i * 3 + 2];
  qnorm[i] = (float)(r0 * r0 + r1 * r1 + r2 * r2);
}

// ---------------- K3: per-node residual mean over neighbors ----------------
__global__ __launch_bounds__(256) void dst_kernel(
    const int* __restrict__ colp, const float* __restrict__ qn,
    float* __restrict__ dout) {
  int i = blockIdx.x * blockDim.x + threadIdx.x;
  if (i >= NS) return;
  const int* ci = colp + i * DEG;
  float s = 0.f;
#pragma unroll
  for (int e = 0; e < DEG; ++e) s += qn[ci[e]];
  dout[i] = s * (1.0f / 32.0f);
}

extern "C" void kernel_launch(void* const* d_in, const int* in_sizes, int n_in,
                              void* d_out, int out_size, void* d_ws, size_t ws_size,
                              hipStream_t stream) {
  const float* sf  = (const float*)d_in[0];   // [N,128]
  const float* tf  = (const float*)d_in[1];   // [T,128]
  const float* tp  = (const float*)d_in[2];   // [T,3]
  const float* pos = (const float*)d_in[3];   // [N,3]
  const int*   ei  = (const int*)d_in[4];     // [2,E]
  float* out = (float*)d_out;                 // [N*9 | N*3 | N]
  char* ws = (char*)d_ws;
  // ws layout (~2.07 MB; qn aliases tfb which is dead after topk):
  float*          tn    = (float*)(ws);                   // 27,648 B
  float*          tn256 = (float*)(ws + 28672);           // 27,648 B
  float*          pred  = (float*)(ws + 57344);           // 240,000 B
  unsigned short* tfb   = (unsigned short*)(ws + 297472); // 1,769,472 B
  float*          qn    = (float*)(ws + 297472);          // alias (post-topk)
  const int* colp = ei + EDG;

  tn_cast_kernel<<<(TPAD * 64) / 256, 256, 0, stream>>>(tf, tn, tn256, tfb);
  topk_wave_kernel<<<NS / 32, 512, 0, stream>>>(sf, tf, tfb, tn, tn256, tp, pred);
  proc_kernel<<<(NS + 255) / 256, 256, 0, stream>>>(colp, pos, pred, out,
                                                    out + NS * 9, qn);
  dst_kernel<<<(NS + 255) / 256, 256, 0, stream>>>(colp, qn, out + NS * 12);
}

// Round 5
// 361.805 us; speedup vs baseline: 3.7310x; 1.0151x over previous
//
#include <hip/hip_runtime.h>
#include <math.h>

#define NS 20000
#define TT 6890
#define TPAD 6912
#define FE 128
#define EDG 640000
#define DEG 32
#define CH 8              // col-chunks per block (one per wave)
#define SPC 27            // strips of 32 cols per chunk; 8*27*32 = 6912 = TPAD

typedef __attribute__((ext_vector_type(8))) short short8;     // 8 bf16
typedef __attribute__((ext_vector_type(4))) float floatx4;    // MFMA C/D
typedef unsigned int uint;

__device__ __forceinline__ unsigned short f2bf(float f) {
  unsigned int u = __float_as_uint(f);
  return (unsigned short)((u + 0x7fffu + ((u >> 16) & 1u)) >> 16);  // RNE
}

// ---------------- K0: target norms (+biased copy) + bf16 cast, padded ----------------
__global__ void tn_cast_kernel(const float* __restrict__ tf, float* __restrict__ tn,
                               float* __restrict__ tn256,
                               unsigned short* __restrict__ tfb) {
  int gid = blockIdx.x * blockDim.x + threadIdx.x;
  int w = gid >> 6;
  int lane = gid & 63;
  if (w >= TPAD) return;
  if (w < TT) {
    const float* p = tf + (size_t)w * FE;
    float a = p[lane];
    float b = p[lane + 64];
    float s = a * a + b * b;
#pragma unroll
    for (int off = 32; off > 0; off >>= 1) s += __shfl_xor(s, off);
    if (lane == 0) { tn[w] = s; tn256[w] = s + 256.0f; }
    float c0 = p[2 * lane], c1 = p[2 * lane + 1];
    ushort2 o;
    o.x = f2bf(c0);
    o.y = f2bf(c1);
    *reinterpret_cast<ushort2*>(tfb + (size_t)w * FE + 2 * lane) = o;
  } else {
    if (lane == 0) { tn[w] = 1e30f; tn256[w] = 3e38f; }  // pads never selected
    ushort2 z; z.x = 0; z.y = 0;
    *reinterpret_cast<ushort2*>(tfb + (size_t)w * FE + 2 * lane) = z;
  }
}

// ---------------- K1: wave-autonomous MFMA, ping-pong prefetch, shfl merge ----------------
// Wave = 32 source rows x one T-chunk (A = target strip -> D-row = tcol,
// B = source rows -> D-col = srow). Per-(lane,h) top-6 packed keys:
// key = (bits(met) & ~0x1FFF) | col, met = tn+256-2*dp > 0 (uint order ==
// float order). Strip s+1 fragments are prefetched into the other register
// buffer before strip s is consumed, so insert-VALU hides L2 latency.
__global__ __launch_bounds__(512, 2) void topk_wave_kernel(
    const float* __restrict__ sf, const float* __restrict__ tf,
    const unsigned short* __restrict__ tfb, const float* __restrict__ tn,
    const float* __restrict__ tn256, const float* __restrict__ tp,
    float* __restrict__ pred) {
  __shared__ uint  pk[32][49];       // merged 48 keys per row
  __shared__ float pv[32][49];       // fp32 rescored dists

  const int tid = threadIdx.x;
  const int lane = tid & 63;
  const int wv = tid >> 6;                 // T-chunk id 0..7
  const int q = lane >> 4;
  const int m = lane & 15;
  const int srow0 = blockIdx.x * 32;

  // resident B-operand fragments: sf rows {srow0+h*16+m}, bf16
  short8 bfr[2][4];
#pragma unroll
  for (int h = 0; h < 2; ++h) {
    const float* src = sf + (size_t)(srow0 + h * 16 + m) * FE;
#pragma unroll
    for (int ks = 0; ks < 4; ++ks) {
      float4 f0 = *reinterpret_cast<const float4*>(src + ks * 32 + q * 8);
      float4 f1 = *reinterpret_cast<const float4*>(src + ks * 32 + q * 8 + 4);
      union { unsigned short us[8]; short8 s8; } t;
      t.us[0] = f2bf(f0.x); t.us[1] = f2bf(f0.y);
      t.us[2] = f2bf(f0.z); t.us[3] = f2bf(f0.w);
      t.us[4] = f2bf(f1.x); t.us[5] = f2bf(f1.y);
      t.us[6] = f2bf(f1.z); t.us[7] = f2bf(f1.w);
      bfr[h][ks] = t.s8;
    }
  }

  uint kq[2][6];
#pragma unroll
  for (int h = 0; h < 2; ++h)
#pragma unroll
    for (int k = 0; k < 6; ++k) kq[h][k] = 0xFFFFFFFFu;

  const int colbase = wv * (SPC * 32);

  short8 af[2][2][4];                // [buf][a][ks]
  float4 tnb[2][2];                  // [buf][a]

  // prefetch strip 0 into buffer 0
  {
#pragma unroll
    for (int a = 0; a < 2; ++a) {
      const unsigned short* base = tfb + (size_t)(colbase + a * 16 + m) * FE;
#pragma unroll
      for (int ks = 0; ks < 4; ++ks)
        af[0][a][ks] = *reinterpret_cast<const short8*>(base + ks * 32 + q * 8);
    }
    tnb[0][0] = *reinterpret_cast<const float4*>(tn256 + colbase + q * 4);
    tnb[0][1] = *reinterpret_cast<const float4*>(tn256 + colbase + 16 + q * 4);
  }

#pragma unroll 2
  for (int s = 0; s < SPC; ++s) {
    const int cur = s & 1, nxt = cur ^ 1;
    if (s + 1 < SPC) {               // prefetch next strip (loads stay in flight)
      const int tc1 = colbase + (s + 1) * 32;
#pragma unroll
      for (int a = 0; a < 2; ++a) {
        const unsigned short* base = tfb + (size_t)(tc1 + a * 16 + m) * FE;
#pragma unroll
        for (int ks = 0; ks < 4; ++ks)
          af[nxt][a][ks] = *reinterpret_cast<const short8*>(base + ks * 32 + q * 8);
      }
      tnb[nxt][0] = *reinterpret_cast<const float4*>(tn256 + tc1 + q * 4);
      tnb[nxt][1] = *reinterpret_cast<const float4*>(tn256 + tc1 + 16 + q * 4);
    }

    const int tcol0 = colbase + s * 32;
    floatx4 acc[2][2];
#pragma unroll
    for (int a = 0; a < 2; ++a)
#pragma unroll
      for (int h = 0; h < 2; ++h) acc[a][h] = (floatx4){0.f, 0.f, 0.f, 0.f};
#pragma unroll
    for (int ks = 0; ks < 4; ++ks) {
      acc[0][0] = __builtin_amdgcn_mfma_f32_16x16x32_bf16(af[cur][0][ks], bfr[0][ks], acc[0][0], 0, 0, 0);
      acc[0][1] = __builtin_amdgcn_mfma_f32_16x16x32_bf16(af[cur][0][ks], bfr[1][ks], acc[0][1], 0, 0, 0);
      acc[1][0] = __builtin_amdgcn_mfma_f32_16x16x32_bf16(af[cur][1][ks], bfr[0][ks], acc[1][0], 0, 0, 0);
      acc[1][1] = __builtin_amdgcn_mfma_f32_16x16x32_bf16(af[cur][1][ks], bfr[1][ks], acc[1][1], 0, 0, 0);
    }

#pragma unroll
    for (int a = 0; a < 2; ++a) {
      const uint cba = (uint)((tcol0 + a * 16) | (q << 2));
      float tv[4] = {tnb[cur][a].x, tnb[cur][a].y, tnb[cur][a].z, tnb[cur][a].w};
#pragma unroll
      for (int r = 0; r < 4; ++r) {
        const uint cbr = cba | (uint)r;
#pragma unroll
        for (int h = 0; h < 2; ++h) {
          float met = fmaf(-2.f, acc[a][h][r], tv[r]);        // > 0 always
          uint t = (__float_as_uint(met) & 0xFFFFE000u) | cbr;
#pragma unroll
          for (int k = 0; k < 6; ++k) {                        // branchless insert
            uint lo = min(kq[h][k], t);
            uint hi = max(kq[h][k], t);
            kq[h][k] = lo;
            t = hi;
          }
        }
      }
    }
  }

  // butterfly shfl merge across the 4 q-lanes -> per (row, chunk) top-6 of 24
#pragma unroll
  for (int h = 0; h < 2; ++h) {
#pragma unroll
    for (int st = 16; st <= 32; st <<= 1) {
      uint inc[6];
#pragma unroll
      for (int k = 0; k < 6; ++k) inc[k] = __shfl_xor(kq[h][k], st);
#pragma unroll
      for (int k = 0; k < 6; ++k) {
        uint t = inc[k];
#pragma unroll
        for (int j = 0; j < 6; ++j) {
          uint lo = min(kq[h][j], t);
          uint hi = max(kq[h][j], t);
          kq[h][j] = lo;
          t = hi;
        }
      }
    }
  }
  if (q == 0) {
#pragma unroll
    for (int h = 0; h < 2; ++h)
#pragma unroll
      for (int k = 0; k < 6; ++k) pk[h * 16 + m][wv * 6 + k] = kq[h][k];
  }
  __syncthreads();

  // fp32 rescore, exact round-1 arithmetic (16 threads/row x 3 cands = 48)
  {
    int r = tid >> 4, p = tid & 15;
    const float* srow = sf + (size_t)(srow0 + r) * FE;
#pragma unroll
    for (int k = 0; k < 3; ++k) {
      int c = (int)(pk[r][p * 3 + k] & 0x1FFFu);
      const float* trow = tf + (size_t)c * FE;
      float accv = 0.f;
#pragma unroll 8
      for (int kk = 0; kk < FE; kk += 4) {
        float4 av = *reinterpret_cast<const float4*>(srow + kk);
        float4 bv = *reinterpret_cast<const float4*>(trow + kk);
        accv += av.x * bv.x + av.y * bv.y + av.z * bv.z + av.w * bv.w;
      }
      pv[r][p * 3 + k] = tn[c] - 2.f * accv;
    }
  }
  __syncthreads();

  // exact top-6 of 48, softmax, gather
  if (tid < 32) {
    int g = srow0 + tid;
    float sd[6]; int sp6[6];
#pragma unroll
    for (int k = 0; k < 6; ++k) { sd[k] = 1e30f; sp6[k] = 0; }
    for (int j = 0; j < 48; ++j) {
      float v = pv[tid][j];
      if (v < sd[5]) {
        sd[5] = v; sp6[5] = j;
#pragma unroll
        for (int k = 4; k >= 0; --k) {
          if (sd[k + 1] < sd[k]) {
            float tvv = sd[k]; sd[k] = sd[k + 1]; sd[k + 1] = tvv;
            int tii = sp6[k]; sp6[k] = sp6[k + 1]; sp6[k + 1] = tii;
          }
        }
      }
    }
    float w[6]; float wsum = 0.f;
#pragma unroll
    for (int k = 0; k < 6; ++k) { w[k] = __expf(sd[0] - sd[k]); wsum += w[k]; }
    float inv = 1.f / wsum;
    float px = 0.f, py = 0.f, pz = 0.f;
#pragma unroll
    for (int k = 0; k < 6; ++k) {
      float sc = w[k] * inv;
      const float* qq = tp + (size_t)(pk[tid][sp6[k]] & 0x1FFFu) * 3;
      px += sc * qq[0]; py += sc * qq[1]; pz += sc * qq[2];
    }
    pred[g * 3 + 0] = px;
    pred[g * 3 + 1] = py;
    pred[g * 3 + 2] = pz;
  }
}

// ---------------- K2: per-node Procrustes (3x3 SVD, fp64 Jacobi) ----------------
__global__ __launch_bounds__(256) void proc_kernel(
    const int* __restrict__ colp, const float* __restrict__ pos,
    const float* __restrict__ pred, float* __restrict__ Rout,
    float* __restrict__ tout, float* __restrict__ qnorm) {
  int i = blockIdx.x * blockDim.x + threadIdx.x;
  if (i >= NS) return;
  double sp[3] = {0, 0, 0}, sq[3] = {0, 0, 0};
  double spq[3][3] = {{0, 0, 0}, {0, 0, 0}, {0, 0, 0}};
  const int* ci = colp + i * DEG;
  for (int e = 0; e < DEG; ++e) {
    int c = ci[e];
    double p0 = pos[c * 3], p1 = pos[c * 3 + 1], p2 = pos[c * 3 + 2];
    double q0 = pred[c * 3], q1 = pred[c * 3 + 1], q2 = pred[c * 3 + 2];
    sp[0] += p0; sp[1] += p1; sp[2] += p2;
    sq[0] += q0; sq[1] += q1; sq[2] += q2;
    spq[0][0] += p0 * q0; spq[0][1] += p0 * q1; spq[0][2] += p0 * q2;
    spq[1][0] += p1 * q0; spq[1][1] += p1 * q1; spq[1][2] += p1 * q2;
    spq[2][0] += p2 * q0; spq[2][1] += p2 * q1; spq[2][2] += p2 * q2;
  }
  const double inv = 1.0 / 32.0;
  double A[3][3], sc[3], tcn[3];
  for (int a = 0; a < 3; ++a) {
    sc[a] = sp[a] * inv;
    tcn[a] = sq[a] * inv;
  }
  for (int a = 0; a < 3; ++a)
    for (int b = 0; b < 3; ++b) A[a][b] = spq[a][b] - sp[a] * sq[b] * inv;

  double S[3][3];
  for (int a = 0; a < 3; ++a)
    for (int b = 0; b < 3; ++b)
      S[a][b] = A[0][a] * A[0][b] + A[1][a] * A[1][b] + A[2][a] * A[2][b];
  double V[3][3] = {{1, 0, 0}, {0, 1, 0}, {0, 0, 1}};
  const int JP[3] = {0, 0, 1}, JQ[3] = {1, 2, 2};
  for (int sweep = 0; sweep < 6; ++sweep) {
    for (int r = 0; r < 3; ++r) {
      int p = JP[r], q = JQ[r];
      double apq = S[p][q];
      if (fabs(apq) < 1e-300) continue;
      double theta = (S[q][q] - S[p][p]) / (2.0 * apq);
      double t = copysign(1.0 / (fabs(theta) + sqrt(theta * theta + 1.0)), theta);
      double c = 1.0 / sqrt(t * t + 1.0);
      double s = t * c;
      double spp = S[p][p], sqq = S[q][q];
      S[p][p] = spp - t * apq;
      S[q][q] = sqq + t * apq;
      S[p][q] = 0.0; S[q][p] = 0.0;
      int k = 3 - p - q;
      double skp = S[k][p], skq = S[k][q];
      S[k][p] = S[p][k] = c * skp - s * skq;
      S[k][q] = S[q][k] = s * skp + c * skq;
      for (int mth = 0; mth < 3; ++mth) {
        double vp = V[mth][p], vq = V[mth][q];
        V[mth][p] = c * vp - s * vq;
        V[mth][q] = s * vp + c * vq;
      }
    }
  }
  double lam[3] = {S[0][0], S[1][1], S[2][2]};
  int i0 = 0, i1 = 1, i2 = 2, tmp;
  if (lam[i0] < lam[i1]) { tmp = i0; i0 = i1; i1 = tmp; }
  if (lam[i0] < lam[i2]) { tmp = i0; i0 = i2; i2 = tmp; }
  if (lam[i1] < lam[i2]) { tmp = i1; i1 = i2; i2 = tmp; }
  double v0[3] = {V[0][i0], V[1][i0], V[2][i0]};
  double v1[3] = {V[0][i1], V[1][i1], V[2][i1]};
  double v2[3] = {V[0][i2], V[1][i2], V[2][i2]};

  double Av0[3], Av1[3], Av2[3];
  for (int a = 0; a < 3; ++a) {
    Av0[a] = A[a][0] * v0[0] + A[a][1] * v0[1] + A[a][2] * v0[2];
    Av1[a] = A[a][0] * v1[0] + A[a][1] * v1[1] + A[a][2] * v1[2];
    Av2[a] = A[a][0] * v2[0] + A[a][1] * v2[1] + A[a][2] * v2[2];
  }
  double n0 = fmax(sqrt(Av0[0]*Av0[0] + Av0[1]*Av0[1] + Av0[2]*Av0[2]), 1e-300);
  double u0[3] = {Av0[0] / n0, Av0[1] / n0, Av0[2] / n0};
  double proj = u0[0]*Av1[0] + u0[1]*Av1[1] + u0[2]*Av1[2];
  double u1[3] = {Av1[0] - proj * u0[0], Av1[1] - proj * u0[1], Av1[2] - proj * u0[2]};
  double n1 = fmax(sqrt(u1[0]*u1[0] + u1[1]*u1[1] + u1[2]*u1[2]), 1e-300);
  u1[0] /= n1; u1[1] /= n1; u1[2] /= n1;
  double w[3] = {u0[1]*u1[2] - u0[2]*u1[1],
                 u0[2]*u1[0] - u0[0]*u1[2],
                 u0[0]*u1[1] - u0[1]*u1[0]};
  double dotw = Av2[0]*w[0] + Av2[1]*w[1] + Av2[2]*w[2];
  double sgn = (dotw < 0.0) ? -1.0 : 1.0;
  double detA = A[0][0]*(A[1][1]*A[2][2] - A[1][2]*A[2][1])
              - A[0][1]*(A[1][0]*A[2][2] - A[1][2]*A[2][0])
              + A[0][2]*(A[1][0]*A[2][1] - A[1][1]*A[2][0]);
  double d3 = ((detA < 0.0) ? -1.0 : 1.0) * sgn;

  double R[3][3];
  for (int a = 0; a < 3; ++a)
    for (int b = 0; b < 3; ++b)
      R[a][b] = u0[a]*v0[b] + u1[a]*v1[b] + d3 * w[a]*v2[b];

  for (int a = 0; a < 3; ++a)
    for (int b = 0; b < 3; ++b) Rout[i * 9 + a * 3 + b] = (float)R[a][b];
  double tr_[3];
  for (int a = 0; a < 3; ++a) {
    tr_[a] = tcn[a] - (R[a][0]*sc[0] + R[a][1]*sc[1] + R[a][2]*sc[2]);
    tout[i * 3 + a] = (float)tr_[a];
  }
  double pxi = pos[i * 3], pyi = pos[i * 3 + 1], pzi = pos[i * 3 + 2];
  double r0 = R[0][0]*pxi + R[0][1]*pyi + R[0][2]*pzi + tr_[0] - pred[i * 3];
  double r1 = R[1][0]*pxi + R[1][1]*pyi + R[1][2]*pzi + tr_[1] - pred[i * 3 + 1];
  double r2 = R[2][0]*pxi + R[2][1]*pyi + R[2][2]*pzi + tr_[2] - pred[i * 3 + 2];
  qnorm[i] = (float)(r0 * r0 + r1 * r1 + r2 * r2);
}

// ---------------- K3: per-node residual mean over neighbors ----------------
__global__ __launch_bounds__(256) void dst_kernel(
    const int* __restrict__ colp, const float* __restrict__ qn,
    float* __restrict__ dout) {
  int i = blockIdx.x * blockDim.x + threadIdx.x;
  if (i >= NS) return;
  const int* ci = colp + i * DEG;
  float s = 0.f;
#pragma unroll
  for (int e = 0; e < DEG; ++e) s += qn[ci[e]];
  dout[i] = s * (1.0f / 32.0f);
}

extern "C" void kernel_launch(void* const* d_in, const int* in_sizes, int n_in,
                              void* d_out, int out_size, void* d_ws, size_t ws_size,
                              hipStream_t stream) {
  const float* sf  = (const float*)d_in[0];   // [N,128]
  const float* tf  = (const float*)d_in[1];   // [T,128]
  const float* tp  = (const float*)d_in[2];   // [T,3]
  const float* pos = (const float*)d_in[3];   // [N,3]
  const int*   ei  = (const int*)d_in[4];     // [2,E]
  float* out = (float*)d_out;                 // [N*9 | N*3 | N]
  char* ws = (char*)d_ws;
  // ws layout (~2.07 MB; qn aliases tfb which is dead after topk):
  float*          tn    = (float*)(ws);                   // 27,648 B
  float*          tn256 = (float*)(ws + 28672);           // 27,648 B
  float*          pred  = (float*)(ws + 57344);           // 240,000 B
  unsigned short* tfb   = (unsigned short*)(ws + 297472); // 1,769,472 B
  float*          qn    = (float*)(ws + 297472);          // alias (post-topk)
  const int* colp = ei + EDG;

  tn_cast_kernel<<<(TPAD * 64) / 256, 256, 0, stream>>>(tf, tn, tn256, tfb);
  topk_wave_kernel<<<NS / 32, 512, 0, stream>>>(sf, tf, tfb, tn, tn256, tp, pred);
  proc_kernel<<<(NS + 255) / 256, 256, 0, stream>>>(colp, pos, pred, out,
                                                    out + NS * 9, qn);
  dst_kernel<<<(NS + 255) / 256, 256, 0, stream>>>(colp, qn, out + NS * 12);
}

// Round 6
// 285.259 us; speedup vs baseline: 4.7322x; 1.2683x over previous
//
#include <hip/hip_runtime.h>
#include <math.h>

#define NS 20000
#define TT 6890
#define TPAD 6912
#define FE 128
#define EDG 640000
#define DEG 32

#define ROWS_PB 80        // 5 waves x 16 source rows
#define NTHR 320
#define SCOLS 64          // target cols per strip
#define NSTRIP 108        // 6912 / 64
#define ASTR 136          // LDS tile row stride in shorts (128+8): 2-way conflicts only

typedef __attribute__((ext_vector_type(8))) short short8;     // 8 bf16
typedef __attribute__((ext_vector_type(4))) float floatx4;    // MFMA C/D
typedef unsigned int uint;

__device__ __forceinline__ unsigned short f2bf(float f) {
  unsigned int u = __float_as_uint(f);
  return (unsigned short)((u + 0x7fffu + ((u >> 16) & 1u)) >> 16);  // RNE
}

// ---------------- K0: target norms (+biased copy) + bf16 cast, padded ----------------
__global__ void tn_cast_kernel(const float* __restrict__ tf, float* __restrict__ tn,
                               float* __restrict__ tn256,
                               unsigned short* __restrict__ tfb) {
  int gid = blockIdx.x * blockDim.x + threadIdx.x;
  int w = gid >> 6;
  int lane = gid & 63;
  if (w >= TPAD) return;
  if (w < TT) {
    const float* p = tf + (size_t)w * FE;
    float a = p[lane];
    float b = p[lane + 64];
    float s = a * a + b * b;
#pragma unroll
    for (int off = 32; off > 0; off >>= 1) s += __shfl_xor(s, off);
    if (lane == 0) { tn[w] = s; tn256[w] = s + 256.0f; }
    float c0 = p[2 * lane], c1 = p[2 * lane + 1];
    ushort2 o;
    o.x = f2bf(c0);
    o.y = f2bf(c1);
    *reinterpret_cast<ushort2*>(tfb + (size_t)w * FE + 2 * lane) = o;
  } else {
    if (lane == 0) { tn[w] = 1e30f; tn256[w] = 3e38f; }  // pads never selected
    ushort2 z; z.x = 0; z.y = 0;
    *reinterpret_cast<ushort2*>(tfb + (size_t)w * FE + 2 * lane) = z;
  }
}

// ---------------- K1: block-shared LDS A-stream + register top-k ----------------
// Block = 80 source rows (5 waves x 16), iterates all 108 target strips.
// Strip tile (64 cols x 128 bf16 + 64 tn) staged to LDS double-buffered.
// MFMA: A = target strip (D-row = tcol), B = source rows (D-col = srow m).
// Per-lane top-6 packed keys: key = (bits(met) & ~0x1FFF) | col,
// met = tn+256-2*dp > 0 so uint order == float order. 12-op bubble insert.
union SmemU {
  struct {
    unsigned short tile[2][SCOLS * ASTR];  // 2 x 17408 B
    float tnl[2][SCOLS];                   // 2 x 256 B
  } s;
  struct {
    uint  pk[ROWS_PB][25];                 // 24 candidates + pad
    float pv[ROWS_PB][25];
  } e;
};

__global__ __launch_bounds__(NTHR, 2) void topk_kernel(
    const float* __restrict__ sf, const float* __restrict__ tf,
    const unsigned short* __restrict__ tfb, const float* __restrict__ tn,
    const float* __restrict__ tn256, const float* __restrict__ tp,
    float* __restrict__ pred) {
  __shared__ SmemU u;
  const int tid = threadIdx.x;
  const int lane = tid & 63;
  const int w = tid >> 6;          // wave 0..4
  const int q = lane >> 4;
  const int m = lane & 15;
  const int rg = blockIdx.x;
  const int row = rg * ROWS_PB + w * 16 + m;   // exact: 250*80 = 20000

  // resident B-operand fragments: sf[row], bf16
  short8 bfr0, bfr1, bfr2, bfr3;
  {
    const float* src = sf + (size_t)row * FE;
#pragma unroll
    for (int ks = 0; ks < 4; ++ks) {
      float4 f0 = *reinterpret_cast<const float4*>(src + ks * 32 + q * 8);
      float4 f1 = *reinterpret_cast<const float4*>(src + ks * 32 + q * 8 + 4);
      union { unsigned short us[8]; short8 s8; } t;
      t.us[0] = f2bf(f0.x); t.us[1] = f2bf(f0.y);
      t.us[2] = f2bf(f0.z); t.us[3] = f2bf(f0.w);
      t.us[4] = f2bf(f1.x); t.us[5] = f2bf(f1.y);
      t.us[6] = f2bf(f1.z); t.us[7] = f2bf(f1.w);
      if (ks == 0) bfr0 = t.s8;
      else if (ks == 1) bfr1 = t.s8;
      else if (ks == 2) bfr2 = t.s8;
      else bfr3 = t.s8;
    }
  }

  uint kq[6];
#pragma unroll
  for (int k = 0; k < 6; ++k) kq[k] = 0xFFFFFFFFu;

  const int s0 = (rg * 13) % NSTRIP;   // stagger strip order across blocks

  // staging registers
  uint4 st0, st1, st2, st3;
  float4 stn;
  const int scl = tid >> 2;            // staging col 0..63 (tid<256)
  const int sqq = tid & 3;             // 64B quarter

  // prologue: load + write strip s0 into buffer 0
  {
    const int s = s0;
    if (tid < 256) {
      const uint4* g = reinterpret_cast<const uint4*>(
          tfb + ((size_t)(s * SCOLS + scl) << 7) + (sqq << 5));
      st0 = g[0]; st1 = g[1]; st2 = g[2]; st3 = g[3];
      unsigned short* d = &u.s.tile[0][scl * ASTR + (sqq << 5)];
      *reinterpret_cast<uint4*>(d)      = st0;
      *reinterpret_cast<uint4*>(d + 8)  = st1;
      *reinterpret_cast<uint4*>(d + 16) = st2;
      *reinterpret_cast<uint4*>(d + 24) = st3;
    } else if (tid < 272) {
      stn = *reinterpret_cast<const float4*>(tn256 + s * SCOLS + ((tid - 256) << 2));
      *reinterpret_cast<float4*>(&u.s.tnl[0][(tid - 256) << 2]) = stn;
    }
  }
  __syncthreads();

  for (int ss = 0; ss < NSTRIP; ++ss) {
    const int p = ss & 1;
    int s = s0 + ss; if (s >= NSTRIP) s -= NSTRIP;
    // prefetch next strip to registers (in flight during compute)
    if (ss + 1 < NSTRIP) {
      int s1 = s0 + ss + 1; if (s1 >= NSTRIP) s1 -= NSTRIP;
      if (tid < 256) {
        const uint4* g = reinterpret_cast<const uint4*>(
            tfb + ((size_t)(s1 * SCOLS + scl) << 7) + (sqq << 5));
        st0 = g[0]; st1 = g[1]; st2 = g[2]; st3 = g[3];
      } else if (tid < 272) {
        stn = *reinterpret_cast<const float4*>(tn256 + s1 * SCOLS + ((tid - 256) << 2));
      }
    }

    const int scol = s * SCOLS;
    const unsigned short* tb = &u.s.tile[p][0];
    const float* tl = &u.s.tnl[p][0];
#pragma unroll
    for (int a = 0; a < 4; ++a) {
      const unsigned short* ab = tb + (a * 16 + m) * ASTR + q * 8;
      short8 a0 = *reinterpret_cast<const short8*>(ab);
      short8 a1 = *reinterpret_cast<const short8*>(ab + 32);
      short8 a2 = *reinterpret_cast<const short8*>(ab + 64);
      short8 a3 = *reinterpret_cast<const short8*>(ab + 96);
      floatx4 acc = (floatx4){0.f, 0.f, 0.f, 0.f};
      acc = __builtin_amdgcn_mfma_f32_16x16x32_bf16(a0, bfr0, acc, 0, 0, 0);
      acc = __builtin_amdgcn_mfma_f32_16x16x32_bf16(a1, bfr1, acc, 0, 0, 0);
      acc = __builtin_amdgcn_mfma_f32_16x16x32_bf16(a2, bfr2, acc, 0, 0, 0);
      acc = __builtin_amdgcn_mfma_f32_16x16x32_bf16(a3, bfr3, acc, 0, 0, 0);
      float4 tv = *reinterpret_cast<const float4*>(&tl[a * 16 + q * 4]);
      const uint cb = (uint)(scol + a * 16 + q * 4);
      float tvv[4] = {tv.x, tv.y, tv.z, tv.w};
#pragma unroll
      for (int r = 0; r < 4; ++r) {
        float met = fmaf(-2.f, acc[r], tvv[r]);           // > 0 always
        uint t = (__float_as_uint(met) & 0xFFFFE000u) | (cb + (uint)r);
#pragma unroll
        for (int k = 0; k < 6; ++k) {                      // branchless insert
          uint lo = min(kq[k], t);
          uint hi = max(kq[k], t);
          kq[k] = lo;
          t = hi;
        }
      }
    }

    // write prefetched strip into the other buffer
    if (ss + 1 < NSTRIP) {
      if (tid < 256) {
        unsigned short* d = &u.s.tile[p ^ 1][scl * ASTR + (sqq << 5)];
        *reinterpret_cast<uint4*>(d)      = st0;
        *reinterpret_cast<uint4*>(d + 8)  = st1;
        *reinterpret_cast<uint4*>(d + 16) = st2;
        *reinterpret_cast<uint4*>(d + 24) = st3;
      } else if (tid < 272) {
        *reinterpret_cast<float4*>(&u.s.tnl[p ^ 1][(tid - 256) << 2]) = stn;
      }
    }
    __syncthreads();
  }

  // dump all 24 candidates per row (4 q-lanes x 6) — no lossy merge
#pragma unroll
  for (int k = 0; k < 6; ++k) u.e.pk[w * 16 + m][q * 6 + k] = kq[k];
  __syncthreads();

  // fp32 rescore: 80 rows x 24 cands = 1920 dots over 320 threads
#pragma unroll
  for (int j = 0; j < 6; ++j) {
    int idx = j * NTHR + tid;          // < 1920
    int r = idx / 24;
    int c = idx - r * 24;
    int col = (int)(u.e.pk[r][c] & 0x1FFFu);
    const float* srow = sf + (size_t)(rg * ROWS_PB + r) * FE;
    const float* trow = tf + (size_t)col * FE;
    float accv = 0.f;
#pragma unroll 8
    for (int kk = 0; kk < FE; kk += 4) {
      float4 av = *reinterpret_cast<const float4*>(srow + kk);
      float4 bv = *reinterpret_cast<const float4*>(trow + kk);
      accv += av.x * bv.x + av.y * bv.y + av.z * bv.z + av.w * bv.w;
    }
    u.e.pv[r][c] = tn[col] - 2.f * accv;
  }
  __syncthreads();

  // exact top-6 of 24, softmax, gather
  if (tid < ROWS_PB) {
    float sd[6]; int sp6[6];
#pragma unroll
    for (int k = 0; k < 6; ++k) { sd[k] = 1e30f; sp6[k] = 0; }
    for (int j = 0; j < 24; ++j) {
      float v = u.e.pv[tid][j];
      if (v < sd[5]) {
        sd[5] = v; sp6[5] = j;
#pragma unroll
        for (int k = 4; k >= 0; --k) {
          if (sd[k + 1] < sd[k]) {
            float tvv = sd[k]; sd[k] = sd[k + 1]; sd[k + 1] = tvv;
            int tii = sp6[k]; sp6[k] = sp6[k + 1]; sp6[k + 1] = tii;
          }
        }
      }
    }
    float wgt[6]; float wsum = 0.f;
#pragma unroll
    for (int k = 0; k < 6; ++k) { wgt[k] = __expf(sd[0] - sd[k]); wsum += wgt[k]; }
    float inv = 1.f / wsum;
    float px = 0.f, py = 0.f, pz = 0.f;
#pragma unroll
    for (int k = 0; k < 6; ++k) {
      float sc = wgt[k] * inv;
      const float* qq = tp + (size_t)(u.e.pk[tid][sp6[k]] & 0x1FFFu) * 3;
      px += sc * qq[0]; py += sc * qq[1]; pz += sc * qq[2];
    }
    int g = rg * ROWS_PB + tid;
    pred[g * 3 + 0] = px;
    pred[g * 3 + 1] = py;
    pred[g * 3 + 2] = pz;
  }
}

// ---------------- K2: per-node Procrustes (3x3 SVD, fp64 Jacobi) ----------------
__global__ __launch_bounds__(256) void proc_kernel(
    const int* __restrict__ colp, const float* __restrict__ pos,
    const float* __restrict__ pred, float* __restrict__ Rout,
    float* __restrict__ tout, float* __restrict__ qnorm) {
  int i = blockIdx.x * blockDim.x + threadIdx.x;
  if (i >= NS) return;
  double sp[3] = {0, 0, 0}, sq[3] = {0, 0, 0};
  double spq[3][3] = {{0, 0, 0}, {0, 0, 0}, {0, 0, 0}};
  const int* ci = colp + i * DEG;
  for (int e = 0; e < DEG; ++e) {
    int c = ci[e];
    double p0 = pos[c * 3], p1 = pos[c * 3 + 1], p2 = pos[c * 3 + 2];
    double q0 = pred[c * 3], q1 = pred[c * 3 + 1], q2 = pred[c * 3 + 2];
    sp[0] += p0; sp[1] += p1; sp[2] += p2;
    sq[0] += q0; sq[1] += q1; sq[2] += q2;
    spq[0][0] += p0 * q0; spq[0][1] += p0 * q1; spq[0][2] += p0 * q2;
    spq[1][0] += p1 * q0; spq[1][1] += p1 * q1; spq[1][2] += p1 * q2;
    spq[2][0] += p2 * q0; spq[2][1] += p2 * q1; spq[2][2] += p2 * q2;
  }
  const double inv = 1.0 / 32.0;
  double A[3][3], sc[3], tcn[3];
  for (int a = 0; a < 3; ++a) {
    sc[a] = sp[a] * inv;
    tcn[a] = sq[a] * inv;
  }
  for (int a = 0; a < 3; ++a)
    for (int b = 0; b < 3; ++b) A[a][b] = spq[a][b] - sp[a] * sq[b] * inv;

  double S[3][3];
  for (int a = 0; a < 3; ++a)
    for (int b = 0; b < 3; ++b)
      S[a][b] = A[0][a] * A[0][b] + A[1][a] * A[1][b] + A[2][a] * A[2][b];
  double V[3][3] = {{1, 0, 0}, {0, 1, 0}, {0, 0, 1}};
  const int JP[3] = {0, 0, 1}, JQ[3] = {1, 2, 2};
  for (int sweep = 0; sweep < 6; ++sweep) {
    for (int r = 0; r < 3; ++r) {
      int p = JP[r], q = JQ[r];
      double apq = S[p][q];
      if (fabs(apq) < 1e-300) continue;
      double theta = (S[q][q] - S[p][p]) / (2.0 * apq);
      double t = copysign(1.0 / (fabs(theta) + sqrt(theta * theta + 1.0)), theta);
      double c = 1.0 / sqrt(t * t + 1.0);
      double s = t * c;
      double spp = S[p][p], sqq = S[q][q];
      S[p][p] = spp - t * apq;
      S[q][q] = sqq + t * apq;
      S[p][q] = 0.0; S[q][p] = 0.0;
      int k = 3 - p - q;
      double skp = S[k][p], skq = S[k][q];
      S[k][p] = S[p][k] = c * skp - s * skq;
      S[k][q] = S[q][k] = s * skp + c * skq;
      for (int mth = 0; mth < 3; ++mth) {
        double vp = V[mth][p], vq = V[mth][q];
        V[mth][p] = c * vp - s * vq;
        V[mth][q] = s * vp + c * vq;
      }
    }
  }
  double lam[3] = {S[0][0], S[1][1], S[2][2]};
  int i0 = 0, i1 = 1, i2 = 2, tmp;
  if (lam[i0] < lam[i1]) { tmp = i0; i0 = i1; i1 = tmp; }
  if (lam[i0] < lam[i2]) { tmp = i0; i0 = i2; i2 = tmp; }
  if (lam[i1] < lam[i2]) { tmp = i1; i1 = i2; i2 = tmp; }
  double v0[3] = {V[0][i0], V[1][i0], V[2][i0]};
  double v1[3] = {V[0][i1], V[1][i1], V[2][i1]};
  double v2[3] = {V[0][i2], V[1][i2], V[2][i2]};

  double Av0[3], Av1[3], Av2[3];
  for (int a = 0; a < 3; ++a) {
    Av0[a] = A[a][0] * v0[0] + A[a][1] * v0[1] + A[a][2] * v0[2];
    Av1[a] = A[a][0] * v1[0] + A[a][1] * v1[1] + A[a][2] * v1[2];
    Av2[a] = A[a][0] * v2[0] + A[a][1] * v2[1] + A[a][2] * v2[2];
  }
  double n0 = fmax(sqrt(Av0[0]*Av0[0] + Av0[1]*Av0[1] + Av0[2]*Av0[2]), 1e-300);
  double u0[3] = {Av0[0] / n0, Av0[1] / n0, Av0[2] / n0};
  double proj = u0[0]*Av1[0] + u0[1]*Av1[1] + u0[2]*Av1[2];
  double u1[3] = {Av1[0] - proj * u0[0], Av1[1] - proj * u0[1], Av1[2] - proj * u0[2]};
  double n1 = fmax(sqrt(u1[0]*u1[0] + u1[1]*u1[1] + u1[2]*u1[2]), 1e-300);
  u1[0] /= n1; u1[1] /= n1; u1[2] /= n1;
  double w[3] = {u0[1]*u1[2] - u0[2]*u1[1],
                 u0[2]*u1[0] - u0[0]*u1[2],
                 u0[0]*u1[1] - u0[1]*u1[0]};
  double dotw = Av2[0]*w[0] + Av2[1]*w[1] + Av2[2]*w[2];
  double sgn = (dotw < 0.0) ? -1.0 : 1.0;
  double detA = A[0][0]*(A[1][1]*A[2][2] - A[1][2]*A[2][1])
              - A[0][1]*(A[1][0]*A[2][2] - A[1][2]*A[2][0])
              + A[0][2]*(A[1][0]*A[2][1] - A[1][1]*A[2][0]);
  double d3 = ((detA < 0.0) ? -1.0 : 1.0) * sgn;

  double R[3][3];
  for (int a = 0; a < 3; ++a)
    for (int b = 0; b < 3; ++b)
      R[a][b] = u0[a]*v0[b] + u1[a]*v1[b] + d3 * w[a]*v2[b];

  for (int a = 0; a < 3; ++a)
    for (int b = 0; b < 3; ++b) Rout[i * 9 + a * 3 + b] = (float)R[a][b];
  double tr_[3];
  for (int a = 0; a < 3; ++a) {
    tr_[a] = tcn[a] - (R[a][0]*sc[0] + R[a][1]*sc[1] + R[a][2]*sc[2]);
    tout[i * 3 + a] = (float)tr_[a];
  }
  double pxi = pos[i * 3], pyi = pos[i * 3 + 1], pzi = pos[i * 3 + 2];
  double r0 = R[0][0]*pxi + R[0][1]*pyi + R[0][2]*pzi + tr_[0] - pred[i * 3];
  double r1 = R[1][0]*pxi + R[1][1]*pyi + R[1][2]*pzi + tr_[1] - pred[i * 3 + 1];
  double r2 = R[2][0]*pxi + R[2][1]*pyi + R[2][2]*pzi + tr_[2] - pred[i * 3 + 2];
  qnorm[i] = (float)(r0 * r0 + r1 * r1 + r2 * r2);
}

// ---------------- K3: per-node residual mean over neighbors ----------------
__global__ __launch_bounds__(256) void dst_kernel(
    const int* __restrict__ colp, const float* __restrict__ qn,
    float* __restrict__ dout) {
  int i = blockIdx.x * blockDim.x + threadIdx.x;
  if (i >= NS) return;
  const int* ci = colp + i * DEG;
  float s = 0.f;
#pragma unroll
  for (int e = 0; e < DEG; ++e) s += qn[ci[e]];
  dout[i] = s * (1.0f / 32.0f);
}

extern "C" void kernel_launch(void* const* d_in, const int* in_sizes, int n_in,
                              void* d_out, int out_size, void* d_ws, size_t ws_size,
                              hipStream_t stream) {
  const float* sf  = (const float*)d_in[0];   // [N,128]
  const float* tf  = (const float*)d_in[1];   // [T,128]
  const float* tp  = (const float*)d_in[2];   // [T,3]
  const float* pos = (const float*)d_in[3];   // [N,3]
  const int*   ei  = (const int*)d_in[4];     // [2,E]
  float* out = (float*)d_out;                 // [N*9 | N*3 | N]
  char* ws = (char*)d_ws;
  // ws layout (~2.07 MB; qn aliases tfb which is dead after topk):
  float*          tn    = (float*)(ws);                   // 27,648 B
  float*          tn256 = (float*)(ws + 28672);           // 27,648 B
  float*          pred  = (float*)(ws + 57344);           // 240,000 B
  unsigned short* tfb   = (unsigned short*)(ws + 297472); // 1,769,472 B
  float*          qn    = (float*)(ws + 297472);          // alias (post-topk)
  const int* colp = ei + EDG;

  tn_cast_kernel<<<(TPAD * 64) / 256, 256, 0, stream>>>(tf, tn, tn256, tfb);
  topk_kernel<<<NS / ROWS_PB, NTHR, 0, stream>>>(sf, tf, tfb, tn, tn256, tp, pred);
  proc_kernel<<<(NS + 255) / 256, 256, 0, stream>>>(colp, pos, pred, out,
                                                    out + NS * 9, qn);
  dst_kernel<<<(NS + 255) / 256, 256, 0, stream>>>(colp, qn, out + NS * 12);
}